// Round 1
// baseline (3099.557 us; speedup 1.0000x reference)
//
#include <hip/hip_runtime.h>
#include <math.h>

// Problem constants
#define BB 2
#define SS 2048
#define DD 1024
#define HH 16
#define HDIM 64
#define NTOK (BB * SS)  // 4096

// ---------------------------------------------------------------------------
// Kernel 1: QKV projection GEMM.
// C[n, d] = sum_k x[n, k] * W[k, d], written to [B][H][S][HD] layout.
// Tile: BM=BN=64, BK=16. 256 threads, each computes 4x4.
// blockIdx.z selects Wq/Wk/Wv.
// ---------------------------------------------------------------------------
__global__ __launch_bounds__(256) void qkv_gemm_kernel(
    const float* __restrict__ x,
    const float* __restrict__ Wq, const float* __restrict__ Wk,
    const float* __restrict__ Wv,
    float* __restrict__ Q, float* __restrict__ K, float* __restrict__ V)
{
    const int which = blockIdx.z;
    const float* W = (which == 0) ? Wq : (which == 1) ? Wk : Wv;
    float* Out = (which == 0) ? Q : (which == 1) ? K : V;

    const int row0 = blockIdx.y * 64;
    const int col0 = blockIdx.x * 64;

    __shared__ float As[16][64 + 1];  // [kk][m]
    __shared__ float Bs[16][64 + 1];  // [kk][n]

    const int tid = threadIdx.x;
    const int tx = tid & 15;   // 0..15 -> output col group
    const int ty = tid >> 4;   // 0..15 -> output row group

    float acc[4][4] = {{0.f}};

    for (int k0 = 0; k0 < DD; k0 += 16) {
        // Load A tile 64x16 (k contiguous within a row of x)
        {
            int r = tid >> 2;            // 0..63
            int kk = (tid & 3) * 4;      // 0,4,8,12
            const float4 v4 = *reinterpret_cast<const float4*>(
                x + (size_t)(row0 + r) * DD + k0 + kk);
            As[kk + 0][r] = v4.x;
            As[kk + 1][r] = v4.y;
            As[kk + 2][r] = v4.z;
            As[kk + 3][r] = v4.w;
        }
        // Load B tile 16x64 (cols contiguous within a row of W)
        {
            int kk = tid >> 4;           // 0..15
            int c = (tid & 15) * 4;      // 0..60
            const float4 v4 = *reinterpret_cast<const float4*>(
                W + (size_t)(k0 + kk) * DD + col0 + c);
            Bs[kk][c + 0] = v4.x;
            Bs[kk][c + 1] = v4.y;
            Bs[kk][c + 2] = v4.z;
            Bs[kk][c + 3] = v4.w;
        }
        __syncthreads();

        #pragma unroll
        for (int kk = 0; kk < 16; ++kk) {
            float a[4], b[4];
            #pragma unroll
            for (int i = 0; i < 4; ++i) a[i] = As[kk][ty * 4 + i];
            #pragma unroll
            for (int j = 0; j < 4; ++j) b[j] = Bs[kk][tx * 4 + j];
            #pragma unroll
            for (int i = 0; i < 4; ++i)
                #pragma unroll
                for (int j = 0; j < 4; ++j)
                    acc[i][j] += a[i] * b[j];
        }
        __syncthreads();
    }

    // Store to [B][H][S][HD]
    #pragma unroll
    for (int i = 0; i < 4; ++i) {
        int n = row0 + ty * 4 + i;
        int b = n / SS, s = n % SS;
        #pragma unroll
        for (int j = 0; j < 4; ++j) {
            int d = col0 + tx * 4 + j;
            int h = d >> 6, hd = d & 63;
            Out[(((size_t)b * HH + h) * SS + s) * HDIM + hd] = acc[i][j];
        }
    }
}

// ---------------------------------------------------------------------------
// Kernel 2: causal flash attention, fp32.
// One block per (q-tile of 64 rows, head, batch). 256 threads.
// Online softmax; K/V staged in LDS 64x64 tiles; causal skip of fully-masked
// KV tiles.
// ---------------------------------------------------------------------------
__global__ __launch_bounds__(256) void flash_attn_kernel(
    const float* __restrict__ Q, const float* __restrict__ K,
    const float* __restrict__ V, float* __restrict__ ctx)
{
    const int qb = blockIdx.x;          // q tile index (0..31)
    const int h  = blockIdx.y;          // head
    const int b  = blockIdx.z;          // batch
    const int q0 = qb * 64;

    __shared__ float Qs[64][65];
    __shared__ float Ks[64][65];
    __shared__ float Vs[64][65];
    __shared__ float Sc[64][65];
    __shared__ float red[4][64];
    __shared__ float m_s[64], l_s[64], alpha_s[64];

    const int tid = threadIdx.x;
    const int r  = tid & 63;    // q row within tile
    const int cg = tid >> 6;    // 0..3 -> column group of 16

    const size_t head_base = ((size_t)b * HH + h) * SS;
    const float* Qbase = Q + (head_base + q0) * HDIM;

    // Load Q tile (64x64 floats = 1024 float4s)
    for (int f = tid; f < 64 * 16; f += 256) {
        int rr = f >> 4, c4 = (f & 15) * 4;
        const float4 v4 = *reinterpret_cast<const float4*>(Qbase + rr * HDIM + c4);
        Qs[rr][c4 + 0] = v4.x; Qs[rr][c4 + 1] = v4.y;
        Qs[rr][c4 + 2] = v4.z; Qs[rr][c4 + 3] = v4.w;
    }
    if (tid < 64) { m_s[tid] = -INFINITY; l_s[tid] = 0.f; }

    float Oacc[16];
    #pragma unroll
    for (int j = 0; j < 16; ++j) Oacc[j] = 0.f;

    __syncthreads();

    const int nkv = qb + 1;  // causal: only tiles 0..qb
    for (int kb = 0; kb < nkv; ++kb) {
        const int k0 = kb * 64;
        const float* Kbase = K + (head_base + k0) * HDIM;
        const float* Vbase = V + (head_base + k0) * HDIM;
        for (int f = tid; f < 64 * 16; f += 256) {
            int rr = f >> 4, c4 = (f & 15) * 4;
            float4 kv4 = *reinterpret_cast<const float4*>(Kbase + rr * HDIM + c4);
            Ks[rr][c4 + 0] = kv4.x; Ks[rr][c4 + 1] = kv4.y;
            Ks[rr][c4 + 2] = kv4.z; Ks[rr][c4 + 3] = kv4.w;
            float4 vv4 = *reinterpret_cast<const float4*>(Vbase + rr * HDIM + c4);
            Vs[rr][c4 + 0] = vv4.x; Vs[rr][c4 + 1] = vv4.y;
            Vs[rr][c4 + 2] = vv4.z; Vs[rr][c4 + 3] = vv4.w;
        }
        __syncthreads();

        // Scores: row r, cols cg*16 .. +15, masked+scaled. Partial row max.
        const int qg = q0 + r;
        float pm = -INFINITY;
        #pragma unroll
        for (int cc = 0; cc < 16; ++cc) {
            int c = cg * 16 + cc;
            float s = 0.f;
            #pragma unroll
            for (int d = 0; d < HDIM; ++d) s += Qs[r][d] * Ks[c][d];
            int kg = k0 + c;
            float val = (kg <= qg) ? s * 0.125f : -INFINITY;
            Sc[r][c] = val;
            pm = fmaxf(pm, val);
        }
        red[cg][r] = pm;
        __syncthreads();

        // Per-row: new max + alpha
        if (tid < 64) {
            float mn = fmaxf(fmaxf(red[0][tid], red[1][tid]),
                             fmaxf(red[2][tid], red[3][tid]));
            mn = fmaxf(mn, m_s[tid]);
            alpha_s[tid] = expf(m_s[tid] - mn);
            m_s[tid] = mn;
        }
        __syncthreads();

        // Exponentiate in place + partial sums
        {
            float mrow = m_s[r];
            float ps = 0.f;
            #pragma unroll
            for (int cc = 0; cc < 16; ++cc) {
                int c = cg * 16 + cc;
                float p = expf(Sc[r][c] - mrow);
                Sc[r][c] = p;
                ps += p;
            }
            red[cg][r] = ps;
        }
        __syncthreads();

        if (tid < 64) {
            l_s[tid] = l_s[tid] * alpha_s[tid] +
                       red[0][tid] + red[1][tid] + red[2][tid] + red[3][tid];
        }

        // Accumulate O for row r, output cols cg*16..+15
        {
            float a = alpha_s[r];
            #pragma unroll
            for (int j = 0; j < 16; ++j) Oacc[j] *= a;
            for (int k = 0; k < 64; ++k) {
                float p = Sc[r][k];
                #pragma unroll
                for (int j = 0; j < 16; ++j) Oacc[j] += p * Vs[k][cg * 16 + j];
            }
        }
        __syncthreads();  // protect Ks/Vs/Sc before next iteration
    }

    // Finalize: divide by l, write ctx in [N][D] row-major ([b][s][h][hd])
    float rl = 1.f / l_s[r];
    const int n = b * SS + q0 + r;
    float* dst = ctx + (size_t)n * DD + h * HDIM + cg * 16;
    #pragma unroll
    for (int j = 0; j < 16; ++j) dst[j] = Oacc[j] * rl;
}

// ---------------------------------------------------------------------------
// Kernel 3: output projection GEMM + bias. out[n,d] = ctx[n,:] @ Wo[:,d] + bo[d]
// ---------------------------------------------------------------------------
__global__ __launch_bounds__(256) void out_gemm_kernel(
    const float* __restrict__ ctx, const float* __restrict__ Wo,
    const float* __restrict__ bo, float* __restrict__ out)
{
    const int row0 = blockIdx.y * 64;
    const int col0 = blockIdx.x * 64;

    __shared__ float As[16][64 + 1];
    __shared__ float Bs[16][64 + 1];

    const int tid = threadIdx.x;
    const int tx = tid & 15;
    const int ty = tid >> 4;

    float acc[4][4] = {{0.f}};

    for (int k0 = 0; k0 < DD; k0 += 16) {
        {
            int r = tid >> 2;
            int kk = (tid & 3) * 4;
            const float4 v4 = *reinterpret_cast<const float4*>(
                ctx + (size_t)(row0 + r) * DD + k0 + kk);
            As[kk + 0][r] = v4.x;
            As[kk + 1][r] = v4.y;
            As[kk + 2][r] = v4.z;
            As[kk + 3][r] = v4.w;
        }
        {
            int kk = tid >> 4;
            int c = (tid & 15) * 4;
            const float4 v4 = *reinterpret_cast<const float4*>(
                Wo + (size_t)(k0 + kk) * DD + col0 + c);
            Bs[kk][c + 0] = v4.x;
            Bs[kk][c + 1] = v4.y;
            Bs[kk][c + 2] = v4.z;
            Bs[kk][c + 3] = v4.w;
        }
        __syncthreads();

        #pragma unroll
        for (int kk = 0; kk < 16; ++kk) {
            float a[4], bq[4];
            #pragma unroll
            for (int i = 0; i < 4; ++i) a[i] = As[kk][ty * 4 + i];
            #pragma unroll
            for (int j = 0; j < 4; ++j) bq[j] = Bs[kk][tx * 4 + j];
            #pragma unroll
            for (int i = 0; i < 4; ++i)
                #pragma unroll
                for (int j = 0; j < 4; ++j)
                    acc[i][j] += a[i] * bq[j];
        }
        __syncthreads();
    }

    #pragma unroll
    for (int i = 0; i < 4; ++i) {
        int n = row0 + ty * 4 + i;
        #pragma unroll
        for (int j = 0; j < 4; ++j) {
            int d = col0 + tx * 4 + j;
            out[(size_t)n * DD + d] = acc[i][j] + bo[d];
        }
    }
}

// ---------------------------------------------------------------------------
extern "C" void kernel_launch(void* const* d_in, const int* in_sizes, int n_in,
                              void* d_out, int out_size, void* d_ws, size_t ws_size,
                              hipStream_t stream) {
    const float* x  = (const float*)d_in[0];
    const float* Wq = (const float*)d_in[1];
    const float* Wk = (const float*)d_in[2];
    const float* Wv = (const float*)d_in[3];
    const float* Wo = (const float*)d_in[4];
    const float* bo = (const float*)d_in[5];
    float* out = (float*)d_out;

    const size_t plane = (size_t)NTOK * DD;  // 4M floats = 16 MB
    float* Q   = (float*)d_ws;
    float* K   = Q + plane;
    float* V   = K + plane;
    float* ctx = V + plane;

    // QKV projections: grid (D/64, N/64, 3)
    qkv_gemm_kernel<<<dim3(DD / 64, NTOK / 64, 3), 256, 0, stream>>>(
        x, Wq, Wk, Wv, Q, K, V);

    // Flash attention: grid (S/64, H, B)
    flash_attn_kernel<<<dim3(SS / 64, HH, BB), 256, 0, stream>>>(Q, K, V, ctx);

    // Output projection
    out_gemm_kernel<<<dim3(DD / 64, NTOK / 64), 256, 0, stream>>>(
        ctx, Wo, bo, out);
}

// Round 6
// 315.482 us; speedup vs baseline: 9.8248x; 9.8248x over previous
//
#include <hip/hip_runtime.h>
#include <math.h>

#define BB 2
#define SS 2048
#define DD 1024
#define HH 16
#define HDIM 64
#define NTOK (BB * SS)  // 4096

typedef __attribute__((ext_vector_type(8))) short short8;
typedef __attribute__((ext_vector_type(4))) float f32x4;

__device__ __forceinline__ short f2bf(float f) {
    unsigned u = __builtin_bit_cast(unsigned, f);
    u = (u + 0x7FFFu + ((u >> 16) & 1u)) >> 16;  // round-to-nearest-even
    return (short)u;
}

// ---------------------------------------------------------------------------
// x (f32 [NTOK][DD]) -> bf16
// ---------------------------------------------------------------------------
__global__ __launch_bounds__(256) void convert_x_kernel(
    const float* __restrict__ x, short* __restrict__ xbf)
{
    const size_t idx = ((size_t)blockIdx.x * 256 + threadIdx.x) * 8;
    float4 a = *reinterpret_cast<const float4*>(x + idx);
    float4 b = *reinterpret_cast<const float4*>(x + idx + 4);
    short8 o;
    o[0] = f2bf(a.x); o[1] = f2bf(a.y); o[2] = f2bf(a.z); o[3] = f2bf(a.w);
    o[4] = f2bf(b.x); o[5] = f2bf(b.y); o[6] = f2bf(b.z); o[7] = f2bf(b.w);
    *reinterpret_cast<short8*>(xbf + idx) = o;
}

// ---------------------------------------------------------------------------
// W (f32 [K][N]) -> Wt (bf16 [N][K])  (transpose + convert), z selects matrix
// ---------------------------------------------------------------------------
__global__ __launch_bounds__(256) void convw_kernel(
    const float* __restrict__ Wq, const float* __restrict__ Wk,
    const float* __restrict__ Wv, const float* __restrict__ Wo,
    short* __restrict__ Wtq, short* __restrict__ Wtk,
    short* __restrict__ Wtv, short* __restrict__ Wto)
{
    const int z = blockIdx.z;
    const float* W = (z == 0) ? Wq : (z == 1) ? Wk : (z == 2) ? Wv : Wo;
    short* Wt = (z == 0) ? Wtq : (z == 1) ? Wtk : (z == 2) ? Wtv : Wto;
    const int k0 = blockIdx.x * 64, n0 = blockIdx.y * 64;
    __shared__ float T[64][65];
    const int tid = threadIdx.x;
    for (int i = tid; i < 1024; i += 256) {
        int r = i >> 4, c4 = (i & 15) * 4;
        float4 v = *reinterpret_cast<const float4*>(W + (size_t)(k0 + r) * DD + n0 + c4);
        T[r][c4 + 0] = v.x; T[r][c4 + 1] = v.y; T[r][c4 + 2] = v.z; T[r][c4 + 3] = v.w;
    }
    __syncthreads();
    for (int i = tid; i < 512; i += 256) {
        int n = i >> 3, k8 = (i & 7) * 8;
        short8 o;
        #pragma unroll
        for (int j = 0; j < 8; ++j) o[j] = f2bf(T[k8 + j][n]);
        *reinterpret_cast<short8*>(Wt + (size_t)(n0 + n) * DD + k0 + k8) = o;
    }
}

// ---------------------------------------------------------------------------
// QKV GEMM via MFMA. A = xbf [NTOK][DD], B^T = Wt [N][K].
// 128x128 tile, BK=32, 256 thr (4 waves 2x2, each 64x64 = 4x4 16x16 frags).
// Out: bf16 [b][h][s][hd], which = blockIdx.z.
// ---------------------------------------------------------------------------
#define BKP 40

__global__ __launch_bounds__(256) void qkv_mfma_kernel(
    const short* __restrict__ xbf,
    const short* __restrict__ Wtq, const short* __restrict__ Wtk,
    const short* __restrict__ Wtv,
    short* __restrict__ Q, short* __restrict__ K, short* __restrict__ V)
{
    const int which = blockIdx.z;
    const short* Wt = (which == 0) ? Wtq : (which == 1) ? Wtk : Wtv;
    short* Out = (which == 0) ? Q : (which == 1) ? K : V;

    const int row0 = blockIdx.y * 128;
    const int col0 = blockIdx.x * 128;
    __shared__ short As[128][BKP];
    __shared__ short Bs[128][BKP];

    const int tid = threadIdx.x;
    const int w = tid >> 6, lane = tid & 63;
    const int wm = (w >> 1) * 64, wn = (w & 1) * 64;
    const int lrow = lane & 15, lk = (lane >> 4) * 8;

    f32x4 acc[4][4];
    #pragma unroll
    for (int m = 0; m < 4; ++m)
        #pragma unroll
        for (int n = 0; n < 4; ++n) acc[m][n] = (f32x4){0.f, 0.f, 0.f, 0.f};

    for (int k0 = 0; k0 < DD; k0 += 32) {
        {
            int i = tid;
            #pragma unroll
            for (int it = 0; it < 2; ++it, i += 256) {
                int r = i >> 2, kk = (i & 3) * 8;
                *reinterpret_cast<short8*>(&As[r][kk]) =
                    *reinterpret_cast<const short8*>(xbf + (size_t)(row0 + r) * DD + k0 + kk);
                *reinterpret_cast<short8*>(&Bs[r][kk]) =
                    *reinterpret_cast<const short8*>(Wt + (size_t)(col0 + r) * DD + k0 + kk);
            }
        }
        __syncthreads();
        short8 af[4], bf_[4];
        #pragma unroll
        for (int m = 0; m < 4; ++m)
            af[m] = *reinterpret_cast<const short8*>(&As[wm + m * 16 + lrow][lk]);
        #pragma unroll
        for (int n = 0; n < 4; ++n)
            bf_[n] = *reinterpret_cast<const short8*>(&Bs[wn + n * 16 + lrow][lk]);
        #pragma unroll
        for (int m = 0; m < 4; ++m)
            #pragma unroll
            for (int n = 0; n < 4; ++n)
                acc[m][n] = __builtin_amdgcn_mfma_f32_16x16x32_bf16(
                    af[m], bf_[n], acc[m][n], 0, 0, 0);
        __syncthreads();
    }

    #pragma unroll
    for (int m = 0; m < 4; ++m) {
        #pragma unroll
        for (int r = 0; r < 4; ++r) {
            int tok = row0 + wm + m * 16 + (lane >> 4) * 4 + r;
            int bb = tok >> 11, s = tok & 2047;
            #pragma unroll
            for (int n = 0; n < 4; ++n) {
                int d = col0 + wn + n * 16 + lrow;
                int hh = d >> 6, hd = d & 63;
                Out[(((size_t)bb * HH + hh) * SS + s) * HDIM + hd] = f2bf(acc[m][n][r]);
            }
        }
    }
}

// ---------------------------------------------------------------------------
// V [b][h][s][hd] -> Vt [b][h][hd][s]   (bf16 transpose via LDS tile)
// ---------------------------------------------------------------------------
__global__ __launch_bounds__(256) void transpose_v_kernel(
    const short* __restrict__ V, short* __restrict__ Vt)
{
    const int sb = blockIdx.x, h = blockIdx.y, b = blockIdx.z;
    const int s0 = sb * 64;
    __shared__ short T[64][72];
    const int tid = threadIdx.x;
    const short* src = V + (((size_t)b * HH + h) * SS + s0) * HDIM;
    {
        int i = tid;
        #pragma unroll
        for (int it = 0; it < 2; ++it, i += 256) {
            int r = i >> 3, c8 = (i & 7) * 8;
            *reinterpret_cast<short8*>(&T[r][c8]) =
                *reinterpret_cast<const short8*>(src + r * HDIM + c8);
        }
    }
    __syncthreads();
    short* dst = Vt + ((size_t)b * HH + h) * HDIM * SS + s0;
    {
        int i = tid;
        #pragma unroll
        for (int it = 0; it < 2; ++it, i += 256) {
            int d = i >> 3, s8 = (i & 7) * 8;
            short8 o;
            #pragma unroll
            for (int j = 0; j < 8; ++j) o[j] = T[s8 + j][d];
            *reinterpret_cast<short8*>(dst + (size_t)d * SS + s8) = o;
        }
    }
}

// ---------------------------------------------------------------------------
// Flash attention, MFMA. Block = (q-tile 128, head, batch), 4 waves x 32 rows.
// QK^T and PV on mfma_f32_16x16x32_bf16; online softmax fp32 in registers.
// ---------------------------------------------------------------------------
__global__ __launch_bounds__(256) void attn_mfma_kernel(
    const short* __restrict__ Q, const short* __restrict__ K,
    const short* __restrict__ Vt, short* __restrict__ ctx)
{
    const int qb = (int)gridDim.x - 1 - (int)blockIdx.x;  // heavy tiles first
    const int h = blockIdx.y, b = blockIdx.z;
    const int q0 = qb * 128;

    __shared__ short Ks[64][72];
    __shared__ short Vs[64][72];
    __shared__ short Ps[4][32][76];

    const int tid = threadIdx.x;
    const int w = tid >> 6, lane = tid & 63;
    const int lrow = lane & 15, lgrp = lane >> 4;
    const size_t hb = ((size_t)b * HH + h) * SS;

    // Q fragments hoisted to registers (rows q0 + w*32 + mf*16 + lrow)
    short8 qf[2][2];
    const short* Qb = Q + (hb + q0 + w * 32) * HDIM;
    #pragma unroll
    for (int mf = 0; mf < 2; ++mf)
        #pragma unroll
        for (int kf = 0; kf < 2; ++kf)
            qf[mf][kf] = *reinterpret_cast<const short8*>(
                Qb + (mf * 16 + lrow) * HDIM + kf * 32 + lgrp * 8);

    f32x4 Oa[2][4];
    float mrun[2][4], lrun[2][4];
    #pragma unroll
    for (int mf = 0; mf < 2; ++mf) {
        #pragma unroll
        for (int nf = 0; nf < 4; ++nf) Oa[mf][nf] = (f32x4){0.f, 0.f, 0.f, 0.f};
        #pragma unroll
        for (int r = 0; r < 4; ++r) { mrun[mf][r] = -INFINITY; lrun[mf][r] = 0.f; }
    }

    const int qmin = q0 + w * 32;
    const int nkb = (q0 >> 6) + 2;
    const short* Vbase = Vt + ((size_t)b * HH + h) * HDIM * SS;

    for (int kb = 0; kb < nkb; ++kb) {
        const int kv0 = kb * 64;
        const short* Kb = K + (hb + kv0) * HDIM;
        const short* Vb = Vbase + kv0;
        {
            int i = tid;
            #pragma unroll
            for (int it = 0; it < 2; ++it, i += 256) {
                int r = i >> 3, c8 = (i & 7) * 8;
                *reinterpret_cast<short8*>(&Ks[r][c8]) =
                    *reinterpret_cast<const short8*>(Kb + r * HDIM + c8);
                *reinterpret_cast<short8*>(&Vs[r][c8]) =
                    *reinterpret_cast<const short8*>(Vb + (size_t)r * SS + c8);
            }
        }
        __syncthreads();

        if (kv0 <= qmin + 31) {  // not fully masked for this wave
            // ---- S = Q K^T ----
            f32x4 s[2][4];
            #pragma unroll
            for (int mf = 0; mf < 2; ++mf)
                #pragma unroll
                for (int nf = 0; nf < 4; ++nf) s[mf][nf] = (f32x4){0.f, 0.f, 0.f, 0.f};
            short8 kfr[4][2];
            #pragma unroll
            for (int nf = 0; nf < 4; ++nf)
                #pragma unroll
                for (int kf = 0; kf < 2; ++kf)
                    kfr[nf][kf] = *reinterpret_cast<const short8*>(
                        &Ks[nf * 16 + lrow][kf * 32 + lgrp * 8]);
            #pragma unroll
            for (int mf = 0; mf < 2; ++mf)
                #pragma unroll
                for (int nf = 0; nf < 4; ++nf)
                    #pragma unroll
                    for (int kf = 0; kf < 2; ++kf)
                        s[mf][nf] = __builtin_amdgcn_mfma_f32_16x16x32_bf16(
                            qf[mf][kf], kfr[nf][kf], s[mf][nf], 0, 0, 0);

            // ---- scale + causal mask ----
            const bool diag = (kv0 + 63 > qmin);
            #pragma unroll
            for (int mf = 0; mf < 2; ++mf)
                #pragma unroll
                for (int nf = 0; nf < 4; ++nf)
                    #pragma unroll
                    for (int r = 0; r < 4; ++r) {
                        float v = s[mf][nf][r] * 0.125f;
                        if (diag) {
                            int qg = qmin + mf * 16 + lgrp * 4 + r;
                            int kg = kv0 + nf * 16 + lrow;
                            if (kg > qg) v = -INFINITY;
                        }
                        s[mf][nf][r] = v;
                    }

            // ---- online softmax (rows live in 16-lane groups) ----
            float mnew[2][4], alpha[2][4];
            #pragma unroll
            for (int mf = 0; mf < 2; ++mf)
                #pragma unroll
                for (int r = 0; r < 4; ++r) {
                    float pm = fmaxf(fmaxf(s[mf][0][r], s[mf][1][r]),
                                     fmaxf(s[mf][2][r], s[mf][3][r]));
                    pm = fmaxf(pm, __shfl_xor(pm, 1));
                    pm = fmaxf(pm, __shfl_xor(pm, 2));
                    pm = fmaxf(pm, __shfl_xor(pm, 4));
                    pm = fmaxf(pm, __shfl_xor(pm, 8));
                    float mn = fmaxf(mrun[mf][r], pm);
                    mnew[mf][r] = mn;
                    alpha[mf][r] = expf(mrun[mf][r] - mn);
                    mrun[mf][r] = mn;
                }
            #pragma unroll
            for (int mf = 0; mf < 2; ++mf)
                #pragma unroll
                for (int nf = 0; nf < 4; ++nf)
                    #pragma unroll
                    for (int r = 0; r < 4; ++r)
                        s[mf][nf][r] = expf(s[mf][nf][r] - mnew[mf][r]);
            #pragma unroll
            for (int mf = 0; mf < 2; ++mf)
                #pragma unroll
                for (int r = 0; r < 4; ++r) {
                    float rs = s[mf][0][r] + s[mf][1][r] + s[mf][2][r] + s[mf][3][r];
                    rs += __shfl_xor(rs, 1);
                    rs += __shfl_xor(rs, 2);
                    rs += __shfl_xor(rs, 4);
                    rs += __shfl_xor(rs, 8);
                    lrun[mf][r] = lrun[mf][r] * alpha[mf][r] + rs;
                }
            #pragma unroll
            for (int mf = 0; mf < 2; ++mf)
                #pragma unroll
                for (int nf = 0; nf < 4; ++nf)
                    #pragma unroll
                    for (int r = 0; r < 4; ++r)
                        Oa[mf][nf][r] *= alpha[mf][r];

            // ---- P (D-layout) -> LDS -> A-layout fragments ----
            #pragma unroll
            for (int mf = 0; mf < 2; ++mf)
                #pragma unroll
                for (int nf = 0; nf < 4; ++nf)
                    #pragma unroll
                    for (int r = 0; r < 4; ++r)
                        Ps[w][mf * 16 + lgrp * 4 + r][nf * 16 + lrow] = f2bf(s[mf][nf][r]);
            asm volatile("s_waitcnt lgkmcnt(0)" ::: "memory");
            __builtin_amdgcn_sched_barrier(0);

            short8 pa[2][2], vb_[4][2];
            #pragma unroll
            for (int mf = 0; mf < 2; ++mf)
                #pragma unroll
                for (int kf = 0; kf < 2; ++kf)
                    pa[mf][kf] = *reinterpret_cast<const short8*>(
                        &Ps[w][mf * 16 + lrow][kf * 32 + lgrp * 8]);
            #pragma unroll
            for (int nf = 0; nf < 4; ++nf)
                #pragma unroll
                for (int kf = 0; kf < 2; ++kf)
                    vb_[nf][kf] = *reinterpret_cast<const short8*>(
                        &Vs[nf * 16 + lrow][kf * 32 + lgrp * 8]);
            #pragma unroll
            for (int mf = 0; mf < 2; ++mf)
                #pragma unroll
                for (int nf = 0; nf < 4; ++nf)
                    #pragma unroll
                    for (int kf = 0; kf < 2; ++kf)
                        Oa[mf][nf] = __builtin_amdgcn_mfma_f32_16x16x32_bf16(
                            pa[mf][kf], vb_[nf][kf], Oa[mf][nf], 0, 0, 0);
        }
        __syncthreads();
    }

    // ---- finalize: O / l, write ctx bf16 [tok][d] ----
    #pragma unroll
    for (int mf = 0; mf < 2; ++mf)
        #pragma unroll
        for (int r = 0; r < 4; ++r) {
            float rl = 1.f / lrun[mf][r];
            int tok = b * SS + q0 + w * 32 + mf * 16 + lgrp * 4 + r;
            #pragma unroll
            for (int nf = 0; nf < 4; ++nf) {
                int d = h * HDIM + nf * 16 + lrow;
                ctx[(size_t)tok * DD + d] = f2bf(Oa[mf][nf][r] * rl);
            }
        }
}

// ---------------------------------------------------------------------------
// Output projection: out = ctx @ Wo + bo (f32 out). Same tile as QKV GEMM.
// ---------------------------------------------------------------------------
__global__ __launch_bounds__(256) void out_mfma_kernel(
    const short* __restrict__ ctxbf, const short* __restrict__ Wto,
    const float* __restrict__ bo, float* __restrict__ out)
{
    const int row0 = blockIdx.y * 128;
    const int col0 = blockIdx.x * 128;
    __shared__ short As[128][BKP];
    __shared__ short Bs[128][BKP];

    const int tid = threadIdx.x;
    const int w = tid >> 6, lane = tid & 63;
    const int wm = (w >> 1) * 64, wn = (w & 1) * 64;
    const int lrow = lane & 15, lk = (lane >> 4) * 8;

    f32x4 acc[4][4];
    #pragma unroll
    for (int m = 0; m < 4; ++m)
        #pragma unroll
        for (int n = 0; n < 4; ++n) acc[m][n] = (f32x4){0.f, 0.f, 0.f, 0.f};

    for (int k0 = 0; k0 < DD; k0 += 32) {
        {
            int i = tid;
            #pragma unroll
            for (int it = 0; it < 2; ++it, i += 256) {
                int r = i >> 2, kk = (i & 3) * 8;
                *reinterpret_cast<short8*>(&As[r][kk]) =
                    *reinterpret_cast<const short8*>(ctxbf + (size_t)(row0 + r) * DD + k0 + kk);
                *reinterpret_cast<short8*>(&Bs[r][kk]) =
                    *reinterpret_cast<const short8*>(Wto + (size_t)(col0 + r) * DD + k0 + kk);
            }
        }
        __syncthreads();
        short8 af[4], bf_[4];
        #pragma unroll
        for (int m = 0; m < 4; ++m)
            af[m] = *reinterpret_cast<const short8*>(&As[wm + m * 16 + lrow][lk]);
        #pragma unroll
        for (int n = 0; n < 4; ++n)
            bf_[n] = *reinterpret_cast<const short8*>(&Bs[wn + n * 16 + lrow][lk]);
        #pragma unroll
        for (int m = 0; m < 4; ++m)
            #pragma unroll
            for (int n = 0; n < 4; ++n)
                acc[m][n] = __builtin_amdgcn_mfma_f32_16x16x32_bf16(
                    af[m], bf_[n], acc[m][n], 0, 0, 0);
        __syncthreads();
    }

    #pragma unroll
    for (int m = 0; m < 4; ++m) {
        #pragma unroll
        for (int r = 0; r < 4; ++r) {
            int tok = row0 + wm + m * 16 + (lane >> 4) * 4 + r;
            #pragma unroll
            for (int n = 0; n < 4; ++n) {
                int d = col0 + wn + n * 16 + lrow;
                out[(size_t)tok * DD + d] = acc[m][n][r] + bo[d];
            }
        }
    }
}

// ---------------------------------------------------------------------------
extern "C" void kernel_launch(void* const* d_in, const int* in_sizes, int n_in,
                              void* d_out, int out_size, void* d_ws, size_t ws_size,
                              hipStream_t stream) {
    const float* x  = (const float*)d_in[0];
    const float* Wq = (const float*)d_in[1];
    const float* Wk = (const float*)d_in[2];
    const float* Wv = (const float*)d_in[3];
    const float* Wo = (const float*)d_in[4];
    const float* bo = (const float*)d_in[5];
    float* out = (float*)d_out;

    const size_t plane = (size_t)NTOK * DD;  // 4M elems
    const size_t wsz   = (size_t)DD * DD;    // 1M elems
    short* xbf  = (short*)d_ws;
    short* Wtq  = xbf + plane;
    short* Wtk  = Wtq + wsz;
    short* Wtv  = Wtk + wsz;
    short* Wto  = Wtv + wsz;
    short* Qb   = Wto + wsz;
    short* Kb   = Qb + plane;
    short* Vb   = Kb + plane;
    short* Vtb  = Vb + plane;
    short* ctxb = Vtb + plane;
    // total = 4M + 4*1M + 5*4M shorts = 56 MB

    convert_x_kernel<<<dim3((unsigned)(plane / (256 * 8))), 256, 0, stream>>>(x, xbf);
    convw_kernel<<<dim3(16, 16, 4), 256, 0, stream>>>(Wq, Wk, Wv, Wo, Wtq, Wtk, Wtv, Wto);
    qkv_mfma_kernel<<<dim3(DD / 128, NTOK / 128, 3), 256, 0, stream>>>(
        xbf, Wtq, Wtk, Wtv, Qb, Kb, Vb);
    transpose_v_kernel<<<dim3(SS / 64, HH, BB), 256, 0, stream>>>(Vb, Vtb);
    attn_mfma_kernel<<<dim3(SS / 128, HH, BB), 256, 0, stream>>>(Qb, Kb, Vtb, ctxb);
    out_mfma_kernel<<<dim3(DD / 128, NTOK / 128), 256, 0, stream>>>(ctxb, Wto, bo, out);
}

// Round 10
// 291.209 us; speedup vs baseline: 10.6438x; 1.0834x over previous
//
#include <hip/hip_runtime.h>
#include <math.h>

#define BB 2
#define SS 2048
#define DD 1024
#define HH 16
#define HDIM 64
#define NTOK (BB * SS)  // 4096

typedef __attribute__((ext_vector_type(8))) short short8;
typedef __attribute__((ext_vector_type(4))) float f32x4;

__device__ __forceinline__ short f2bf(float f) {
    unsigned u = __builtin_bit_cast(unsigned, f);
    u = (u + 0x7FFFu + ((u >> 16) & 1u)) >> 16;  // round-to-nearest-even
    return (short)u;
}

// ---------------------------------------------------------------------------
// x (f32 [NTOK][DD]) -> bf16
// ---------------------------------------------------------------------------
__global__ __launch_bounds__(256) void convert_x_kernel(
    const float* __restrict__ x, short* __restrict__ xbf)
{
    const size_t idx = ((size_t)blockIdx.x * 256 + threadIdx.x) * 8;
    float4 a = *reinterpret_cast<const float4*>(x + idx);
    float4 b = *reinterpret_cast<const float4*>(x + idx + 4);
    short8 o;
    o[0] = f2bf(a.x); o[1] = f2bf(a.y); o[2] = f2bf(a.z); o[3] = f2bf(a.w);
    o[4] = f2bf(b.x); o[5] = f2bf(b.y); o[6] = f2bf(b.z); o[7] = f2bf(b.w);
    *reinterpret_cast<short8*>(xbf + idx) = o;
}

// ---------------------------------------------------------------------------
// W (f32 [K][N]) -> Wt (bf16 [N][K])  (transpose + convert), z selects matrix
// ---------------------------------------------------------------------------
__global__ __launch_bounds__(256) void convw_kernel(
    const float* __restrict__ Wq, const float* __restrict__ Wk,
    const float* __restrict__ Wv, const float* __restrict__ Wo,
    short* __restrict__ Wtq, short* __restrict__ Wtk,
    short* __restrict__ Wtv, short* __restrict__ Wto)
{
    const int z = blockIdx.z;
    const float* W = (z == 0) ? Wq : (z == 1) ? Wk : (z == 2) ? Wv : Wo;
    short* Wt = (z == 0) ? Wtq : (z == 1) ? Wtk : (z == 2) ? Wtv : Wto;
    const int k0 = blockIdx.x * 64, n0 = blockIdx.y * 64;
    __shared__ float T[64][65];
    const int tid = threadIdx.x;
    for (int i = tid; i < 1024; i += 256) {
        int r = i >> 4, c4 = (i & 15) * 4;
        float4 v = *reinterpret_cast<const float4*>(W + (size_t)(k0 + r) * DD + n0 + c4);
        T[r][c4 + 0] = v.x; T[r][c4 + 1] = v.y; T[r][c4 + 2] = v.z; T[r][c4 + 3] = v.w;
    }
    __syncthreads();
    for (int i = tid; i < 512; i += 256) {
        int n = i >> 3, k8 = (i & 7) * 8;
        short8 o;
        #pragma unroll
        for (int j = 0; j < 8; ++j) o[j] = f2bf(T[k8 + j][n]);
        *reinterpret_cast<short8*>(Wt + (size_t)(n0 + n) * DD + k0 + k8) = o;
    }
}

// ---------------------------------------------------------------------------
// QKV GEMM via MFMA. A = xbf [NTOK][DD], B^T = Wt [N][K].
// 128x128 tile, BK=32, 256 thr (4 waves 2x2, each 64x64 = 4x4 16x16 frags).
// Out: bf16 [b][h][s][hd], which = blockIdx.z.
// ---------------------------------------------------------------------------
#define BKP 40

__global__ __launch_bounds__(256) void qkv_mfma_kernel(
    const short* __restrict__ xbf,
    const short* __restrict__ Wtq, const short* __restrict__ Wtk,
    const short* __restrict__ Wtv,
    short* __restrict__ Q, short* __restrict__ K, short* __restrict__ V)
{
    const int which = blockIdx.z;
    const short* Wt = (which == 0) ? Wtq : (which == 1) ? Wtk : Wtv;
    short* Out = (which == 0) ? Q : (which == 1) ? K : V;

    const int row0 = blockIdx.y * 128;
    const int col0 = blockIdx.x * 128;
    __shared__ short As[128][BKP];
    __shared__ short Bs[128][BKP];

    const int tid = threadIdx.x;
    const int w = tid >> 6, lane = tid & 63;
    const int wm = (w >> 1) * 64, wn = (w & 1) * 64;
    const int lrow = lane & 15, lk = (lane >> 4) * 8;

    f32x4 acc[4][4];
    #pragma unroll
    for (int m = 0; m < 4; ++m)
        #pragma unroll
        for (int n = 0; n < 4; ++n) acc[m][n] = (f32x4){0.f, 0.f, 0.f, 0.f};

    for (int k0 = 0; k0 < DD; k0 += 32) {
        {
            int i = tid;
            #pragma unroll
            for (int it = 0; it < 2; ++it, i += 256) {
                int r = i >> 2, kk = (i & 3) * 8;
                *reinterpret_cast<short8*>(&As[r][kk]) =
                    *reinterpret_cast<const short8*>(xbf + (size_t)(row0 + r) * DD + k0 + kk);
                *reinterpret_cast<short8*>(&Bs[r][kk]) =
                    *reinterpret_cast<const short8*>(Wt + (size_t)(col0 + r) * DD + k0 + kk);
            }
        }
        __syncthreads();
        short8 af[4], bf_[4];
        #pragma unroll
        for (int m = 0; m < 4; ++m)
            af[m] = *reinterpret_cast<const short8*>(&As[wm + m * 16 + lrow][lk]);
        #pragma unroll
        for (int n = 0; n < 4; ++n)
            bf_[n] = *reinterpret_cast<const short8*>(&Bs[wn + n * 16 + lrow][lk]);
        #pragma unroll
        for (int m = 0; m < 4; ++m)
            #pragma unroll
            for (int n = 0; n < 4; ++n)
                acc[m][n] = __builtin_amdgcn_mfma_f32_16x16x32_bf16(
                    af[m], bf_[n], acc[m][n], 0, 0, 0);
        __syncthreads();
    }

    #pragma unroll
    for (int m = 0; m < 4; ++m) {
        #pragma unroll
        for (int r = 0; r < 4; ++r) {
            int tok = row0 + wm + m * 16 + (lane >> 4) * 4 + r;
            int bb = tok >> 11, s = tok & 2047;
            #pragma unroll
            for (int n = 0; n < 4; ++n) {
                int d = col0 + wn + n * 16 + lrow;
                int hh = d >> 6, hd = d & 63;
                Out[(((size_t)bb * HH + hh) * SS + s) * HDIM + hd] = f2bf(acc[m][n][r]);
            }
        }
    }
}

// ---------------------------------------------------------------------------
// V [b][h][s][hd] -> Vt [b][h][hd][s]   (bf16 transpose via LDS tile)
// ---------------------------------------------------------------------------
__global__ __launch_bounds__(256) void transpose_v_kernel(
    const short* __restrict__ V, short* __restrict__ Vt)
{
    const int sb = blockIdx.x, h = blockIdx.y, b = blockIdx.z;
    const int s0 = sb * 64;
    __shared__ short T[64][72];
    const int tid = threadIdx.x;
    const short* src = V + (((size_t)b * HH + h) * SS + s0) * HDIM;
    {
        int i = tid;
        #pragma unroll
        for (int it = 0; it < 2; ++it, i += 256) {
            int r = i >> 3, c8 = (i & 7) * 8;
            *reinterpret_cast<short8*>(&T[r][c8]) =
                *reinterpret_cast<const short8*>(src + r * HDIM + c8);
        }
    }
    __syncthreads();
    short* dst = Vt + ((size_t)b * HH + h) * HDIM * SS + s0;
    {
        int i = tid;
        #pragma unroll
        for (int it = 0; it < 2; ++it, i += 256) {
            int d = i >> 3, s8 = (i & 7) * 8;
            short8 o;
            #pragma unroll
            for (int j = 0; j < 8; ++j) o[j] = T[s8 + j][d];
            *reinterpret_cast<short8*>(dst + (size_t)d * SS + s8) = o;
        }
    }
}

// ---------------------------------------------------------------------------
// Flash attention, MFMA, wave-per-tile. One wave (64 thr) owns 32 q-rows.
// No __syncthreads, no K/V LDS staging (K/V are L2-resident; loaded as
// fragments directly from global). Online softmax in log2 domain (exp2).
// Grid (S/32, H, B) = 2048 blocks, heavy tiles first.
// ---------------------------------------------------------------------------
__global__ __launch_bounds__(64) void attn_mfma_kernel(
    const short* __restrict__ Q, const short* __restrict__ K,
    const short* __restrict__ Vt, short* __restrict__ ctx)
{
    const int qt = 63 - (int)blockIdx.x;  // heavy tiles first
    const int h = blockIdx.y, b = blockIdx.z;
    const int q0 = qt * 32;

    __shared__ short Ps[32][76];  // per-wave P relayout buffer (4.9 KB)

    const int lane = threadIdx.x;
    const int lrow = lane & 15, lgrp = lane >> 4;
    const size_t hb = ((size_t)b * HH + h) * SS;

    // scale folded with log2(e): softmax runs in the exp2 domain
    const float SC = 0.125f * 1.44269504088896340736f;

    // Q fragments hoisted to registers (rows q0 + mf*16 + lrow)
    short8 qf[2][2];
    const short* Qb = Q + (hb + q0) * HDIM;
    #pragma unroll
    for (int mf = 0; mf < 2; ++mf)
        #pragma unroll
        for (int kf = 0; kf < 2; ++kf)
            qf[mf][kf] = *reinterpret_cast<const short8*>(
                Qb + (mf * 16 + lrow) * HDIM + kf * 32 + lgrp * 8);

    f32x4 Oa[2][4];
    float mrun[2][4], lrun[2][4];
    #pragma unroll
    for (int mf = 0; mf < 2; ++mf) {
        #pragma unroll
        for (int nf = 0; nf < 4; ++nf) Oa[mf][nf] = (f32x4){0.f, 0.f, 0.f, 0.f};
        #pragma unroll
        for (int r = 0; r < 4; ++r) { mrun[mf][r] = -INFINITY; lrun[mf][r] = 0.f; }
    }

    const int nkb = (qt >> 1) + 1;
    const short* Kbase = K + hb * HDIM;
    const short* Vtb = Vt + ((size_t)b * HH + h) * HDIM * SS;

    for (int kb = 0; kb < nkb; ++kb) {
        const int kv0 = kb * 64;

        // ---- K fragments direct from global (16 contiguous 128B rows/quad) ----
        short8 kfr[4][2];
        #pragma unroll
        for (int nf = 0; nf < 4; ++nf)
            #pragma unroll
            for (int kf = 0; kf < 2; ++kf)
                kfr[nf][kf] = *reinterpret_cast<const short8*>(
                    Kbase + (size_t)(kv0 + nf * 16 + lrow) * HDIM + kf * 32 + lgrp * 8);

        // ---- S = Q K^T ----
        f32x4 s[2][4];
        #pragma unroll
        for (int mf = 0; mf < 2; ++mf)
            #pragma unroll
            for (int nf = 0; nf < 4; ++nf) s[mf][nf] = (f32x4){0.f, 0.f, 0.f, 0.f};
        #pragma unroll
        for (int mf = 0; mf < 2; ++mf)
            #pragma unroll
            for (int nf = 0; nf < 4; ++nf)
                #pragma unroll
                for (int kf = 0; kf < 2; ++kf)
                    s[mf][nf] = __builtin_amdgcn_mfma_f32_16x16x32_bf16(
                        qf[mf][kf], kfr[nf][kf], s[mf][nf], 0, 0, 0);

        // ---- scale (log2 domain) + causal mask ----
        const bool diag = (kv0 + 63 > q0);
        #pragma unroll
        for (int mf = 0; mf < 2; ++mf)
            #pragma unroll
            for (int nf = 0; nf < 4; ++nf)
                #pragma unroll
                for (int r = 0; r < 4; ++r) {
                    float v = s[mf][nf][r] * SC;
                    if (diag) {
                        int qg = q0 + mf * 16 + lgrp * 4 + r;
                        int kg = kv0 + nf * 16 + lrow;
                        if (kg > qg) v = -INFINITY;
                    }
                    s[mf][nf][r] = v;
                }

        // ---- online softmax (rows live in 16-lane groups), exp2 domain ----
        float mnew[2][4], alpha[2][4];
        #pragma unroll
        for (int mf = 0; mf < 2; ++mf)
            #pragma unroll
            for (int r = 0; r < 4; ++r) {
                float pm = fmaxf(fmaxf(s[mf][0][r], s[mf][1][r]),
                                 fmaxf(s[mf][2][r], s[mf][3][r]));
                pm = fmaxf(pm, __shfl_xor(pm, 1));
                pm = fmaxf(pm, __shfl_xor(pm, 2));
                pm = fmaxf(pm, __shfl_xor(pm, 4));
                pm = fmaxf(pm, __shfl_xor(pm, 8));
                float mn = fmaxf(mrun[mf][r], pm);
                mnew[mf][r] = mn;
                alpha[mf][r] = exp2f(mrun[mf][r] - mn);
                mrun[mf][r] = mn;
            }
        #pragma unroll
        for (int mf = 0; mf < 2; ++mf)
            #pragma unroll
            for (int nf = 0; nf < 4; ++nf)
                #pragma unroll
                for (int r = 0; r < 4; ++r)
                    s[mf][nf][r] = exp2f(s[mf][nf][r] - mnew[mf][r]);
        #pragma unroll
        for (int mf = 0; mf < 2; ++mf)
            #pragma unroll
            for (int r = 0; r < 4; ++r) {
                float rs = s[mf][0][r] + s[mf][1][r] + s[mf][2][r] + s[mf][3][r];
                rs += __shfl_xor(rs, 1);
                rs += __shfl_xor(rs, 2);
                rs += __shfl_xor(rs, 4);
                rs += __shfl_xor(rs, 8);
                lrun[mf][r] = lrun[mf][r] * alpha[mf][r] + rs;
            }
        #pragma unroll
        for (int mf = 0; mf < 2; ++mf)
            #pragma unroll
            for (int nf = 0; nf < 4; ++nf)
                #pragma unroll
                for (int r = 0; r < 4; ++r)
                    Oa[mf][nf][r] *= alpha[mf][r];

        // ---- P (D-layout) -> LDS -> A-layout fragments (wave-private) ----
        #pragma unroll
        for (int mf = 0; mf < 2; ++mf)
            #pragma unroll
            for (int nf = 0; nf < 4; ++nf)
                #pragma unroll
                for (int r = 0; r < 4; ++r)
                    Ps[mf * 16 + lgrp * 4 + r][nf * 16 + lrow] = f2bf(s[mf][nf][r]);
        asm volatile("s_waitcnt lgkmcnt(0)" ::: "memory");
        __builtin_amdgcn_sched_barrier(0);

        short8 pa[2][2], vb_[4][2];
        #pragma unroll
        for (int mf = 0; mf < 2; ++mf)
            #pragma unroll
            for (int kf = 0; kf < 2; ++kf)
                pa[mf][kf] = *reinterpret_cast<const short8*>(
                    &Ps[mf * 16 + lrow][kf * 32 + lgrp * 8]);

        // ---- V fragments direct from global (Vt is [hd][s]) ----
        #pragma unroll
        for (int nf = 0; nf < 4; ++nf)
            #pragma unroll
            for (int kf = 0; kf < 2; ++kf)
                vb_[nf][kf] = *reinterpret_cast<const short8*>(
                    Vtb + (size_t)(nf * 16 + lrow) * SS + kv0 + kf * 32 + lgrp * 8);

        #pragma unroll
        for (int mf = 0; mf < 2; ++mf)
            #pragma unroll
            for (int nf = 0; nf < 4; ++nf)
                #pragma unroll
                for (int kf = 0; kf < 2; ++kf)
                    Oa[mf][nf] = __builtin_amdgcn_mfma_f32_16x16x32_bf16(
                        pa[mf][kf], vb_[nf][kf], Oa[mf][nf], 0, 0, 0);
    }

    // ---- finalize: O / l, write ctx bf16 [tok][d] ----
    #pragma unroll
    for (int mf = 0; mf < 2; ++mf)
        #pragma unroll
        for (int r = 0; r < 4; ++r) {
            float rl = 1.f / lrun[mf][r];
            int tok = b * SS + q0 + mf * 16 + lgrp * 4 + r;
            #pragma unroll
            for (int nf = 0; nf < 4; ++nf) {
                int d = h * HDIM + nf * 16 + lrow;
                ctx[(size_t)tok * DD + d] = f2bf(Oa[mf][nf][r] * rl);
            }
        }
}

// ---------------------------------------------------------------------------
// Output projection: out = ctx @ Wo + bo (f32 out). Same tile as QKV GEMM.
// ---------------------------------------------------------------------------
__global__ __launch_bounds__(256) void out_mfma_kernel(
    const short* __restrict__ ctxbf, const short* __restrict__ Wto,
    const float* __restrict__ bo, float* __restrict__ out)
{
    const int row0 = blockIdx.y * 128;
    const int col0 = blockIdx.x * 128;
    __shared__ short As[128][BKP];
    __shared__ short Bs[128][BKP];

    const int tid = threadIdx.x;
    const int w = tid >> 6, lane = tid & 63;
    const int wm = (w >> 1) * 64, wn = (w & 1) * 64;
    const int lrow = lane & 15, lk = (lane >> 4) * 8;

    f32x4 acc[4][4];
    #pragma unroll
    for (int m = 0; m < 4; ++m)
        #pragma unroll
        for (int n = 0; n < 4; ++n) acc[m][n] = (f32x4){0.f, 0.f, 0.f, 0.f};

    for (int k0 = 0; k0 < DD; k0 += 32) {
        {
            int i = tid;
            #pragma unroll
            for (int it = 0; it < 2; ++it, i += 256) {
                int r = i >> 2, kk = (i & 3) * 8;
                *reinterpret_cast<short8*>(&As[r][kk]) =
                    *reinterpret_cast<const short8*>(ctxbf + (size_t)(row0 + r) * DD + k0 + kk);
                *reinterpret_cast<short8*>(&Bs[r][kk]) =
                    *reinterpret_cast<const short8*>(Wto + (size_t)(col0 + r) * DD + k0 + kk);
            }
        }
        __syncthreads();
        short8 af[4], bf_[4];
        #pragma unroll
        for (int m = 0; m < 4; ++m)
            af[m] = *reinterpret_cast<const short8*>(&As[wm + m * 16 + lrow][lk]);
        #pragma unroll
        for (int n = 0; n < 4; ++n)
            bf_[n] = *reinterpret_cast<const short8*>(&Bs[wn + n * 16 + lrow][lk]);
        #pragma unroll
        for (int m = 0; m < 4; ++m)
            #pragma unroll
            for (int n = 0; n < 4; ++n)
                acc[m][n] = __builtin_amdgcn_mfma_f32_16x16x32_bf16(
                    af[m], bf_[n], acc[m][n], 0, 0, 0);
        __syncthreads();
    }

    #pragma unroll
    for (int m = 0; m < 4; ++m) {
        #pragma unroll
        for (int r = 0; r < 4; ++r) {
            int tok = row0 + wm + m * 16 + (lane >> 4) * 4 + r;
            #pragma unroll
            for (int n = 0; n < 4; ++n) {
                int d = col0 + wn + n * 16 + lrow;
                out[(size_t)tok * DD + d] = acc[m][n][r] + bo[d];
            }
        }
    }
}

// ---------------------------------------------------------------------------
extern "C" void kernel_launch(void* const* d_in, const int* in_sizes, int n_in,
                              void* d_out, int out_size, void* d_ws, size_t ws_size,
                              hipStream_t stream) {
    const float* x  = (const float*)d_in[0];
    const float* Wq = (const float*)d_in[1];
    const float* Wk = (const float*)d_in[2];
    const float* Wv = (const float*)d_in[3];
    const float* Wo = (const float*)d_in[4];
    const float* bo = (const float*)d_in[5];
    float* out = (float*)d_out;

    const size_t plane = (size_t)NTOK * DD;  // 4M elems
    const size_t wsz   = (size_t)DD * DD;    // 1M elems
    short* xbf  = (short*)d_ws;
    short* Wtq  = xbf + plane;
    short* Wtk  = Wtq + wsz;
    short* Wtv  = Wtk + wsz;
    short* Wto  = Wtv + wsz;
    short* Qb   = Wto + wsz;
    short* Kb   = Qb + plane;
    short* Vb   = Kb + plane;
    short* Vtb  = Vb + plane;
    short* ctxb = Vtb + plane;
    // total = 4M + 4*1M + 5*4M shorts = 56 MB

    convert_x_kernel<<<dim3((unsigned)(plane / (256 * 8))), 256, 0, stream>>>(x, xbf);
    convw_kernel<<<dim3(16, 16, 4), 256, 0, stream>>>(Wq, Wk, Wv, Wo, Wtq, Wtk, Wtv, Wto);
    qkv_mfma_kernel<<<dim3(DD / 128, NTOK / 128, 3), 256, 0, stream>>>(
        xbf, Wtq, Wtk, Wtv, Qb, Kb, Vb);
    transpose_v_kernel<<<dim3(SS / 64, HH, BB), 256, 0, stream>>>(Vb, Vtb);
    attn_mfma_kernel<<<dim3(SS / 32, HH, BB), 64, 0, stream>>>(Qb, Kb, Vtb, ctxb);
    out_mfma_kernel<<<dim3(DD / 128, NTOK / 128), 256, 0, stream>>>(ctxb, Wto, bo, out);
}

// Round 11
// 281.797 us; speedup vs baseline: 10.9993x; 1.0334x over previous
//
#include <hip/hip_runtime.h>
#include <math.h>

#define BB 2
#define SS 2048
#define DD 1024
#define HH 16
#define HDIM 64
#define NTOK (BB * SS)  // 4096

typedef __attribute__((ext_vector_type(8))) short short8;
typedef __attribute__((ext_vector_type(4))) float f32x4;

__device__ __forceinline__ short f2bf(float f) {
    unsigned u = __builtin_bit_cast(unsigned, f);
    u = (u + 0x7FFFu + ((u >> 16) & 1u)) >> 16;  // round-to-nearest-even
    return (short)u;
}

// ---------------------------------------------------------------------------
// x (f32 [NTOK][DD]) -> bf16
// ---------------------------------------------------------------------------
__global__ __launch_bounds__(256) void convert_x_kernel(
    const float* __restrict__ x, short* __restrict__ xbf)
{
    const size_t idx = ((size_t)blockIdx.x * 256 + threadIdx.x) * 8;
    float4 a = *reinterpret_cast<const float4*>(x + idx);
    float4 b = *reinterpret_cast<const float4*>(x + idx + 4);
    short8 o;
    o[0] = f2bf(a.x); o[1] = f2bf(a.y); o[2] = f2bf(a.z); o[3] = f2bf(a.w);
    o[4] = f2bf(b.x); o[5] = f2bf(b.y); o[6] = f2bf(b.z); o[7] = f2bf(b.w);
    *reinterpret_cast<short8*>(xbf + idx) = o;
}

// ---------------------------------------------------------------------------
// W (f32 [K][N]) -> Wt (bf16 [N][K])  (transpose + convert), z selects matrix
// ---------------------------------------------------------------------------
__global__ __launch_bounds__(256) void convw_kernel(
    const float* __restrict__ Wq, const float* __restrict__ Wk,
    const float* __restrict__ Wv, const float* __restrict__ Wo,
    short* __restrict__ Wtq, short* __restrict__ Wtk,
    short* __restrict__ Wtv, short* __restrict__ Wto)
{
    const int z = blockIdx.z;
    const float* W = (z == 0) ? Wq : (z == 1) ? Wk : (z == 2) ? Wv : Wo;
    short* Wt = (z == 0) ? Wtq : (z == 1) ? Wtk : (z == 2) ? Wtv : Wto;
    const int k0 = blockIdx.x * 64, n0 = blockIdx.y * 64;
    __shared__ float T[64][65];
    const int tid = threadIdx.x;
    for (int i = tid; i < 1024; i += 256) {
        int r = i >> 4, c4 = (i & 15) * 4;
        float4 v = *reinterpret_cast<const float4*>(W + (size_t)(k0 + r) * DD + n0 + c4);
        T[r][c4 + 0] = v.x; T[r][c4 + 1] = v.y; T[r][c4 + 2] = v.z; T[r][c4 + 3] = v.w;
    }
    __syncthreads();
    for (int i = tid; i < 512; i += 256) {
        int n = i >> 3, k8 = (i & 7) * 8;
        short8 o;
        #pragma unroll
        for (int j = 0; j < 8; ++j) o[j] = f2bf(T[k8 + j][n]);
        *reinterpret_cast<short8*>(Wt + (size_t)(n0 + n) * DD + k0 + k8) = o;
    }
}

// ---------------------------------------------------------------------------
// QKV GEMM via MFMA. A = xbf [NTOK][DD], B^T = Wt [N][K].
// 128x128 tile, BK=32, 256 thr (4 waves 2x2, each 64x64 = 4x4 16x16 frags).
// Out: bf16 [b][h][s][hd], which = blockIdx.z.
// ---------------------------------------------------------------------------
#define BKP 40

__global__ __launch_bounds__(256) void qkv_mfma_kernel(
    const short* __restrict__ xbf,
    const short* __restrict__ Wtq, const short* __restrict__ Wtk,
    const short* __restrict__ Wtv,
    short* __restrict__ Q, short* __restrict__ K, short* __restrict__ V)
{
    const int which = blockIdx.z;
    const short* Wt = (which == 0) ? Wtq : (which == 1) ? Wtk : Wtv;
    short* Out = (which == 0) ? Q : (which == 1) ? K : V;

    const int row0 = blockIdx.y * 128;
    const int col0 = blockIdx.x * 128;
    __shared__ short As[128][BKP];
    __shared__ short Bs[128][BKP];

    const int tid = threadIdx.x;
    const int w = tid >> 6, lane = tid & 63;
    const int wm = (w >> 1) * 64, wn = (w & 1) * 64;
    const int lrow = lane & 15, lk = (lane >> 4) * 8;

    f32x4 acc[4][4];
    #pragma unroll
    for (int m = 0; m < 4; ++m)
        #pragma unroll
        for (int n = 0; n < 4; ++n) acc[m][n] = (f32x4){0.f, 0.f, 0.f, 0.f};

    for (int k0 = 0; k0 < DD; k0 += 32) {
        {
            int i = tid;
            #pragma unroll
            for (int it = 0; it < 2; ++it, i += 256) {
                int r = i >> 2, kk = (i & 3) * 8;
                *reinterpret_cast<short8*>(&As[r][kk]) =
                    *reinterpret_cast<const short8*>(xbf + (size_t)(row0 + r) * DD + k0 + kk);
                *reinterpret_cast<short8*>(&Bs[r][kk]) =
                    *reinterpret_cast<const short8*>(Wt + (size_t)(col0 + r) * DD + k0 + kk);
            }
        }
        __syncthreads();
        short8 af[4], bf_[4];
        #pragma unroll
        for (int m = 0; m < 4; ++m)
            af[m] = *reinterpret_cast<const short8*>(&As[wm + m * 16 + lrow][lk]);
        #pragma unroll
        for (int n = 0; n < 4; ++n)
            bf_[n] = *reinterpret_cast<const short8*>(&Bs[wn + n * 16 + lrow][lk]);
        #pragma unroll
        for (int m = 0; m < 4; ++m)
            #pragma unroll
            for (int n = 0; n < 4; ++n)
                acc[m][n] = __builtin_amdgcn_mfma_f32_16x16x32_bf16(
                    af[m], bf_[n], acc[m][n], 0, 0, 0);
        __syncthreads();
    }

    #pragma unroll
    for (int m = 0; m < 4; ++m) {
        #pragma unroll
        for (int r = 0; r < 4; ++r) {
            int tok = row0 + wm + m * 16 + (lane >> 4) * 4 + r;
            int bb = tok >> 11, s = tok & 2047;
            #pragma unroll
            for (int n = 0; n < 4; ++n) {
                int d = col0 + wn + n * 16 + lrow;
                int hh = d >> 6, hd = d & 63;
                Out[(((size_t)bb * HH + hh) * SS + s) * HDIM + hd] = f2bf(acc[m][n][r]);
            }
        }
    }
}

// ---------------------------------------------------------------------------
// V [b][h][s][hd] -> Vt [b][h][hd][s]   (bf16 transpose via LDS tile)
// ---------------------------------------------------------------------------
__global__ __launch_bounds__(256) void transpose_v_kernel(
    const short* __restrict__ V, short* __restrict__ Vt)
{
    const int sb = blockIdx.x, h = blockIdx.y, b = blockIdx.z;
    const int s0 = sb * 64;
    __shared__ short T[64][72];
    const int tid = threadIdx.x;
    const short* src = V + (((size_t)b * HH + h) * SS + s0) * HDIM;
    {
        int i = tid;
        #pragma unroll
        for (int it = 0; it < 2; ++it, i += 256) {
            int r = i >> 3, c8 = (i & 7) * 8;
            *reinterpret_cast<short8*>(&T[r][c8]) =
                *reinterpret_cast<const short8*>(src + r * HDIM + c8);
        }
    }
    __syncthreads();
    short* dst = Vt + ((size_t)b * HH + h) * HDIM * SS + s0;
    {
        int i = tid;
        #pragma unroll
        for (int it = 0; it < 2; ++it, i += 256) {
            int d = i >> 3, s8 = (i & 7) * 8;
            short8 o;
            #pragma unroll
            for (int j = 0; j < 8; ++j) o[j] = T[s8 + j][d];
            *reinterpret_cast<short8*>(dst + (size_t)d * SS + s8) = o;
        }
    }
}

// ---------------------------------------------------------------------------
// Flash attention, MFMA, split-KV. Block = (q-tile of 32 rows, head, batch),
// 256 threads = 4 waves. Wave w handles kv-tiles kb = w, w+4, ... (round
// robin), each keeping private (m, l, O). One __syncthreads, then LDS merge:
// m* = max m_w, O* = sum exp2(m_w-m*) O_w, l* = sum exp2(m_w-m*) l_w.
// K/V fragments direct from L2-resident global; softmax in exp2 domain.
// Each wave's P-relayout buffer aliases its own merge slice (in-order DS).
// ---------------------------------------------------------------------------
__global__ __launch_bounds__(256) void attn_mfma_kernel(
    const short* __restrict__ Q, const short* __restrict__ K,
    const short* __restrict__ Vt, short* __restrict__ ctx)
{
    const int qt = 63 - (int)blockIdx.x;  // heavy tiles first
    const int h = blockIdx.y, b = blockIdx.z;
    const int q0 = qt * 32;

    __shared__ float merge_buf[4][32][68];      // 34.8 KB (O partials, f32)
    __shared__ float mbuf[4][32], lbuf[4][32];  // 1 KB   (m, l partials)

    const int tid = threadIdx.x;
    const int w = tid >> 6, lane = tid & 63;
    const int lrow = lane & 15, lgrp = lane >> 4;
    // wave-private P relayout buffer aliases this wave's merge slice
    // (4.9 KB needed, 8.7 KB available; last Ps read precedes first O write
    //  in this wave's in-order DS stream)
    short (*Ps)[76] = reinterpret_cast<short (*)[76]>(&merge_buf[w][0][0]);

    const size_t hb = ((size_t)b * HH + h) * SS;
    const float SC = 0.125f * 1.44269504088896340736f;  // scale * log2(e)

    // Q fragments hoisted to registers (rows q0 + mf*16 + lrow)
    short8 qf[2][2];
    const short* Qb = Q + (hb + q0) * HDIM;
    #pragma unroll
    for (int mf = 0; mf < 2; ++mf)
        #pragma unroll
        for (int kf = 0; kf < 2; ++kf)
            qf[mf][kf] = *reinterpret_cast<const short8*>(
                Qb + (mf * 16 + lrow) * HDIM + kf * 32 + lgrp * 8);

    f32x4 Oa[2][4];
    float mrun[2][4], lrun[2][4];
    #pragma unroll
    for (int mf = 0; mf < 2; ++mf) {
        #pragma unroll
        for (int nf = 0; nf < 4; ++nf) Oa[mf][nf] = (f32x4){0.f, 0.f, 0.f, 0.f};
        #pragma unroll
        for (int r = 0; r < 4; ++r) { mrun[mf][r] = -INFINITY; lrun[mf][r] = 0.f; }
    }

    const int nkb = (qt >> 1) + 1;  // kv tiles cover [0, q0+32)
    const short* Kbase = K + hb * HDIM;
    const short* Vtb = Vt + ((size_t)b * HH + h) * HDIM * SS;

    for (int kb = w; kb < nkb; kb += 4) {
        const int kv0 = kb * 64;

        // ---- K fragments direct from global (16 contiguous 128B rows/quad) ----
        short8 kfr[4][2];
        #pragma unroll
        for (int nf = 0; nf < 4; ++nf)
            #pragma unroll
            for (int kf = 0; kf < 2; ++kf)
                kfr[nf][kf] = *reinterpret_cast<const short8*>(
                    Kbase + (size_t)(kv0 + nf * 16 + lrow) * HDIM + kf * 32 + lgrp * 8);

        // ---- S = Q K^T ----
        f32x4 s[2][4];
        #pragma unroll
        for (int mf = 0; mf < 2; ++mf)
            #pragma unroll
            for (int nf = 0; nf < 4; ++nf) s[mf][nf] = (f32x4){0.f, 0.f, 0.f, 0.f};
        #pragma unroll
        for (int mf = 0; mf < 2; ++mf)
            #pragma unroll
            for (int nf = 0; nf < 4; ++nf)
                #pragma unroll
                for (int kf = 0; kf < 2; ++kf)
                    s[mf][nf] = __builtin_amdgcn_mfma_f32_16x16x32_bf16(
                        qf[mf][kf], kfr[nf][kf], s[mf][nf], 0, 0, 0);

        // ---- scale (log2 domain) + causal mask ----
        const bool diag = (kv0 + 63 > q0);
        #pragma unroll
        for (int mf = 0; mf < 2; ++mf)
            #pragma unroll
            for (int nf = 0; nf < 4; ++nf)
                #pragma unroll
                for (int r = 0; r < 4; ++r) {
                    float v = s[mf][nf][r] * SC;
                    if (diag) {
                        int qg = q0 + mf * 16 + lgrp * 4 + r;
                        int kg = kv0 + nf * 16 + lrow;
                        if (kg > qg) v = -INFINITY;
                    }
                    s[mf][nf][r] = v;
                }

        // ---- online softmax (rows live in 16-lane groups), exp2 domain ----
        float mnew[2][4], alpha[2][4];
        #pragma unroll
        for (int mf = 0; mf < 2; ++mf)
            #pragma unroll
            for (int r = 0; r < 4; ++r) {
                float pm = fmaxf(fmaxf(s[mf][0][r], s[mf][1][r]),
                                 fmaxf(s[mf][2][r], s[mf][3][r]));
                pm = fmaxf(pm, __shfl_xor(pm, 1));
                pm = fmaxf(pm, __shfl_xor(pm, 2));
                pm = fmaxf(pm, __shfl_xor(pm, 4));
                pm = fmaxf(pm, __shfl_xor(pm, 8));
                float mn = fmaxf(mrun[mf][r], pm);
                mnew[mf][r] = mn;
                alpha[mf][r] = exp2f(mrun[mf][r] - mn);
                mrun[mf][r] = mn;
            }
        #pragma unroll
        for (int mf = 0; mf < 2; ++mf)
            #pragma unroll
            for (int nf = 0; nf < 4; ++nf)
                #pragma unroll
                for (int r = 0; r < 4; ++r)
                    s[mf][nf][r] = exp2f(s[mf][nf][r] - mnew[mf][r]);
        #pragma unroll
        for (int mf = 0; mf < 2; ++mf)
            #pragma unroll
            for (int r = 0; r < 4; ++r) {
                float rs = s[mf][0][r] + s[mf][1][r] + s[mf][2][r] + s[mf][3][r];
                rs += __shfl_xor(rs, 1);
                rs += __shfl_xor(rs, 2);
                rs += __shfl_xor(rs, 4);
                rs += __shfl_xor(rs, 8);
                lrun[mf][r] = lrun[mf][r] * alpha[mf][r] + rs;
            }
        #pragma unroll
        for (int mf = 0; mf < 2; ++mf)
            #pragma unroll
            for (int nf = 0; nf < 4; ++nf)
                #pragma unroll
                for (int r = 0; r < 4; ++r)
                    Oa[mf][nf][r] *= alpha[mf][r];

        // ---- P (D-layout) -> LDS -> A-layout fragments (wave-private) ----
        #pragma unroll
        for (int mf = 0; mf < 2; ++mf)
            #pragma unroll
            for (int nf = 0; nf < 4; ++nf)
                #pragma unroll
                for (int r = 0; r < 4; ++r)
                    Ps[mf * 16 + lgrp * 4 + r][nf * 16 + lrow] = f2bf(s[mf][nf][r]);
        asm volatile("s_waitcnt lgkmcnt(0)" ::: "memory");
        __builtin_amdgcn_sched_barrier(0);

        short8 pa[2][2], vb_[4][2];
        #pragma unroll
        for (int mf = 0; mf < 2; ++mf)
            #pragma unroll
            for (int kf = 0; kf < 2; ++kf)
                pa[mf][kf] = *reinterpret_cast<const short8*>(
                    &Ps[mf * 16 + lrow][kf * 32 + lgrp * 8]);

        // ---- V fragments direct from global (Vt is [hd][s]) ----
        #pragma unroll
        for (int nf = 0; nf < 4; ++nf)
            #pragma unroll
            for (int kf = 0; kf < 2; ++kf)
                vb_[nf][kf] = *reinterpret_cast<const short8*>(
                    Vtb + (size_t)(nf * 16 + lrow) * SS + kv0 + kf * 32 + lgrp * 8);

        #pragma unroll
        for (int mf = 0; mf < 2; ++mf)
            #pragma unroll
            for (int nf = 0; nf < 4; ++nf)
                #pragma unroll
                for (int kf = 0; kf < 2; ++kf)
                    Oa[mf][nf] = __builtin_amdgcn_mfma_f32_16x16x32_bf16(
                        pa[mf][kf], vb_[nf][kf], Oa[mf][nf], 0, 0, 0);
    }

    // ---- write per-wave partials (O aliases this wave's Ps region) ----
    #pragma unroll
    for (int mf = 0; mf < 2; ++mf)
        #pragma unroll
        for (int r = 0; r < 4; ++r) {
            int row = mf * 16 + lgrp * 4 + r;
            if (lrow == 0) {
                mbuf[w][row] = mrun[mf][r];
                lbuf[w][row] = lrun[mf][r];
            }
            #pragma unroll
            for (int nf = 0; nf < 4; ++nf)
                merge_buf[w][row][nf * 16 + lrow] = Oa[mf][nf][r];
        }
    __syncthreads();

    // ---- merge across the 4 KV-split waves: 256 thr x 8 elems ----
    {
        const int row = tid >> 3;
        const int c0 = (tid & 7) * 8;
        float m0 = mbuf[0][row], m1 = mbuf[1][row];
        float m2 = mbuf[2][row], m3 = mbuf[3][row];
        float mg = fmaxf(fmaxf(m0, m1), fmaxf(m2, m3));
        float w0 = exp2f(m0 - mg), w1 = exp2f(m1 - mg);
        float w2 = exp2f(m2 - mg), w3 = exp2f(m3 - mg);
        float lg = w0 * lbuf[0][row] + w1 * lbuf[1][row] +
                   w2 * lbuf[2][row] + w3 * lbuf[3][row];
        float rl = 1.f / lg;
        short8 o8;
        #pragma unroll
        for (int j = 0; j < 8; ++j) {
            float o = w0 * merge_buf[0][row][c0 + j] + w1 * merge_buf[1][row][c0 + j] +
                      w2 * merge_buf[2][row][c0 + j] + w3 * merge_buf[3][row][c0 + j];
            o8[j] = f2bf(o * rl);
        }
        const int tok = b * SS + q0 + row;
        *reinterpret_cast<short8*>(ctx + (size_t)tok * DD + h * HDIM + c0) = o8;
    }
}

// ---------------------------------------------------------------------------
// Output projection: out = ctx @ Wo + bo (f32 out). Same tile as QKV GEMM.
// ---------------------------------------------------------------------------
__global__ __launch_bounds__(256) void out_mfma_kernel(
    const short* __restrict__ ctxbf, const short* __restrict__ Wto,
    const float* __restrict__ bo, float* __restrict__ out)
{
    const int row0 = blockIdx.y * 128;
    const int col0 = blockIdx.x * 128;
    __shared__ short As[128][BKP];
    __shared__ short Bs[128][BKP];

    const int tid = threadIdx.x;
    const int w = tid >> 6, lane = tid & 63;
    const int wm = (w >> 1) * 64, wn = (w & 1) * 64;
    const int lrow = lane & 15, lk = (lane >> 4) * 8;

    f32x4 acc[4][4];
    #pragma unroll
    for (int m = 0; m < 4; ++m)
        #pragma unroll
        for (int n = 0; n < 4; ++n) acc[m][n] = (f32x4){0.f, 0.f, 0.f, 0.f};

    for (int k0 = 0; k0 < DD; k0 += 32) {
        {
            int i = tid;
            #pragma unroll
            for (int it = 0; it < 2; ++it, i += 256) {
                int r = i >> 2, kk = (i & 3) * 8;
                *reinterpret_cast<short8*>(&As[r][kk]) =
                    *reinterpret_cast<const short8*>(ctxbf + (size_t)(row0 + r) * DD + k0 + kk);
                *reinterpret_cast<short8*>(&Bs[r][kk]) =
                    *reinterpret_cast<const short8*>(Wto + (size_t)(col0 + r) * DD + k0 + kk);
            }
        }
        __syncthreads();
        short8 af[4], bf_[4];
        #pragma unroll
        for (int m = 0; m < 4; ++m)
            af[m] = *reinterpret_cast<const short8*>(&As[wm + m * 16 + lrow][lk]);
        #pragma unroll
        for (int n = 0; n < 4; ++n)
            bf_[n] = *reinterpret_cast<const short8*>(&Bs[wn + n * 16 + lrow][lk]);
        #pragma unroll
        for (int m = 0; m < 4; ++m)
            #pragma unroll
            for (int n = 0; n < 4; ++n)
                acc[m][n] = __builtin_amdgcn_mfma_f32_16x16x32_bf16(
                    af[m], bf_[n], acc[m][n], 0, 0, 0);
        __syncthreads();
    }

    #pragma unroll
    for (int m = 0; m < 4; ++m) {
        #pragma unroll
        for (int r = 0; r < 4; ++r) {
            int tok = row0 + wm + m * 16 + (lane >> 4) * 4 + r;
            #pragma unroll
            for (int n = 0; n < 4; ++n) {
                int d = col0 + wn + n * 16 + lrow;
                out[(size_t)tok * DD + d] = acc[m][n][r] + bo[d];
            }
        }
    }
}

// ---------------------------------------------------------------------------
extern "C" void kernel_launch(void* const* d_in, const int* in_sizes, int n_in,
                              void* d_out, int out_size, void* d_ws, size_t ws_size,
                              hipStream_t stream) {
    const float* x  = (const float*)d_in[0];
    const float* Wq = (const float*)d_in[1];
    const float* Wk = (const float*)d_in[2];
    const float* Wv = (const float*)d_in[3];
    const float* Wo = (const float*)d_in[4];
    const float* bo = (const float*)d_in[5];
    float* out = (float*)d_out;

    const size_t plane = (size_t)NTOK * DD;  // 4M elems
    const size_t wsz   = (size_t)DD * DD;    // 1M elems
    short* xbf  = (short*)d_ws;
    short* Wtq  = xbf + plane;
    short* Wtk  = Wtq + wsz;
    short* Wtv  = Wtk + wsz;
    short* Wto  = Wtv + wsz;
    short* Qb   = Wto + wsz;
    short* Kb   = Qb + plane;
    short* Vb   = Kb + plane;
    short* Vtb  = Vb + plane;
    short* ctxb = Vtb + plane;
    // total = 4M + 4*1M + 5*4M shorts = 56 MB

    convert_x_kernel<<<dim3((unsigned)(plane / (256 * 8))), 256, 0, stream>>>(x, xbf);
    convw_kernel<<<dim3(16, 16, 4), 256, 0, stream>>>(Wq, Wk, Wv, Wo, Wtq, Wtk, Wtv, Wto);
    qkv_mfma_kernel<<<dim3(DD / 128, NTOK / 128, 3), 256, 0, stream>>>(
        xbf, Wtq, Wtk, Wtv, Qb, Kb, Vb);
    transpose_v_kernel<<<dim3(SS / 64, HH, BB), 256, 0, stream>>>(Vb, Vtb);
    attn_mfma_kernel<<<dim3(SS / 32, HH, BB), 256, 0, stream>>>(Qb, Kb, Vtb, ctxb);
    out_mfma_kernel<<<dim3(DD / 128, NTOK / 128), 256, 0, stream>>>(ctxb, Wto, bo, out);
}

// Round 12
// 270.829 us; speedup vs baseline: 11.4447x; 1.0405x over previous
//
#include <hip/hip_runtime.h>
#include <math.h>

#define BB 2
#define SS 2048
#define DD 1024
#define HH 16
#define HDIM 64
#define NTOK (BB * SS)  // 4096

typedef __attribute__((ext_vector_type(8))) short short8;
typedef __attribute__((ext_vector_type(4))) short short4v;
typedef __attribute__((ext_vector_type(4))) float f32x4;

__device__ __forceinline__ short f2bf(float f) {
    unsigned u = __builtin_bit_cast(unsigned, f);
    u = (u + 0x7FFFu + ((u >> 16) & 1u)) >> 16;  // round-to-nearest-even
    return (short)u;
}

// async global->LDS, 16B per lane. LDS dest must be wave-uniform base + lane*16.
__device__ __forceinline__ void gl_lds16(const short* g, short* l) {
    __builtin_amdgcn_global_load_lds(
        (const __attribute__((address_space(1))) void*)g,
        (__attribute__((address_space(3))) void*)l, 16, 0, 0);
}

// ---------------------------------------------------------------------------
// x (f32 [NTOK][DD]) -> bf16
// ---------------------------------------------------------------------------
__global__ __launch_bounds__(256) void convert_x_kernel(
    const float* __restrict__ x, short* __restrict__ xbf)
{
    const size_t idx = ((size_t)blockIdx.x * 256 + threadIdx.x) * 8;
    float4 a = *reinterpret_cast<const float4*>(x + idx);
    float4 b = *reinterpret_cast<const float4*>(x + idx + 4);
    short8 o;
    o[0] = f2bf(a.x); o[1] = f2bf(a.y); o[2] = f2bf(a.z); o[3] = f2bf(a.w);
    o[4] = f2bf(b.x); o[5] = f2bf(b.y); o[6] = f2bf(b.z); o[7] = f2bf(b.w);
    *reinterpret_cast<short8*>(xbf + idx) = o;
}

// ---------------------------------------------------------------------------
// W (f32 [K][N]) -> Wt (bf16 [N][K])  (transpose + convert), z selects matrix
// ---------------------------------------------------------------------------
__global__ __launch_bounds__(256) void convw_kernel(
    const float* __restrict__ Wq, const float* __restrict__ Wk,
    const float* __restrict__ Wv, const float* __restrict__ Wo,
    short* __restrict__ Wtq, short* __restrict__ Wtk,
    short* __restrict__ Wtv, short* __restrict__ Wto)
{
    const int z = blockIdx.z;
    const float* W = (z == 0) ? Wq : (z == 1) ? Wk : (z == 2) ? Wv : Wo;
    short* Wt = (z == 0) ? Wtq : (z == 1) ? Wtk : (z == 2) ? Wtv : Wto;
    const int k0 = blockIdx.x * 64, n0 = blockIdx.y * 64;
    __shared__ float T[64][65];
    const int tid = threadIdx.x;
    for (int i = tid; i < 1024; i += 256) {
        int r = i >> 4, c4 = (i & 15) * 4;
        float4 v = *reinterpret_cast<const float4*>(W + (size_t)(k0 + r) * DD + n0 + c4);
        T[r][c4 + 0] = v.x; T[r][c4 + 1] = v.y; T[r][c4 + 2] = v.z; T[r][c4 + 3] = v.w;
    }
    __syncthreads();
    for (int i = tid; i < 512; i += 256) {
        int n = i >> 3, k8 = (i & 7) * 8;
        short8 o;
        #pragma unroll
        for (int j = 0; j < 8; ++j) o[j] = f2bf(T[k8 + j][n]);
        *reinterpret_cast<short8*>(Wt + (size_t)(n0 + n) * DD + k0 + k8) = o;
    }
}

// ---------------------------------------------------------------------------
// QKV GEMM via MFMA + global_load_lds staging (m97 pattern, linear LDS).
// 128x128 tile, BK=32, 256 thr (4 waves 2x2). Q,K out: bf16 [b][h][s][hd];
// V written directly TRANSPOSED to Vt [b][h][hd][s] (fused transpose).
// ---------------------------------------------------------------------------
__global__ __launch_bounds__(256) void qkv_mfma_kernel(
    const short* __restrict__ xbf,
    const short* __restrict__ Wtq, const short* __restrict__ Wtk,
    const short* __restrict__ Wtv,
    short* __restrict__ Q, short* __restrict__ K, short* __restrict__ Vt)
{
    const int which = blockIdx.z;
    const short* Wt = (which == 0) ? Wtq : (which == 1) ? Wtk : Wtv;

    const int row0 = blockIdx.y * 128;
    const int col0 = blockIdx.x * 128;
    __shared__ short As[128 * 32];  // linear [row][32]
    __shared__ short Bs[128 * 32];

    const int tid = threadIdx.x;
    const int w = tid >> 6, lane = tid & 63;
    const int wm = (w >> 1) * 64, wn = (w & 1) * 64;
    const int lrow = lane & 15, lgrp = lane >> 4, lk = lgrp * 8;

    f32x4 acc[4][4];
    #pragma unroll
    for (int m = 0; m < 4; ++m)
        #pragma unroll
        for (int n = 0; n < 4; ++n) acc[m][n] = (f32x4){0.f, 0.f, 0.f, 0.f};

    for (int k0 = 0; k0 < DD; k0 += 32) {
        #pragma unroll
        for (int c = 0; c < 2; ++c) {
            int slot = c * 256 + tid;
            int r = slot >> 2, cb = (slot & 3) * 8;
            gl_lds16(xbf + (size_t)(row0 + r) * DD + k0 + cb, As + slot * 8);
            gl_lds16(Wt + (size_t)(col0 + r) * DD + k0 + cb, Bs + slot * 8);
        }
        __syncthreads();  // drains vmcnt(0): LDS ready
        short8 af[4], bf_[4];
        #pragma unroll
        for (int m = 0; m < 4; ++m)
            af[m] = *reinterpret_cast<const short8*>(&As[(wm + m * 16 + lrow) * 32 + lk]);
        #pragma unroll
        for (int n = 0; n < 4; ++n)
            bf_[n] = *reinterpret_cast<const short8*>(&Bs[(wn + n * 16 + lrow) * 32 + lk]);
        #pragma unroll
        for (int m = 0; m < 4; ++m)
            #pragma unroll
            for (int n = 0; n < 4; ++n)
                acc[m][n] = __builtin_amdgcn_mfma_f32_16x16x32_bf16(
                    af[m], bf_[n], acc[m][n], 0, 0, 0);
        __syncthreads();
    }

    if (which < 2) {
        short* Out = (which == 0) ? Q : K;
        #pragma unroll
        for (int m = 0; m < 4; ++m) {
            #pragma unroll
            for (int r = 0; r < 4; ++r) {
                int tok = row0 + wm + m * 16 + lgrp * 4 + r;
                int bb = tok >> 11, s = tok & 2047;
                #pragma unroll
                for (int n = 0; n < 4; ++n) {
                    int d = col0 + wn + n * 16 + lrow;
                    int hh = d >> 6, hd = d & 63;
                    Out[(((size_t)bb * HH + hh) * SS + s) * HDIM + hd] = f2bf(acc[m][n][r]);
                }
            }
        }
    } else {
        // V: write transposed, [b][h][hd][s]; r-pack = 4 consecutive s -> short4
        #pragma unroll
        for (int m = 0; m < 4; ++m) {
            int tok0 = row0 + wm + m * 16 + lgrp * 4;
            int bb = tok0 >> 11, s0 = tok0 & 2047;
            #pragma unroll
            for (int n = 0; n < 4; ++n) {
                int d = col0 + wn + n * 16 + lrow;
                int hh = d >> 6, hd = d & 63;
                short4v pk;
                pk[0] = f2bf(acc[m][n][0]); pk[1] = f2bf(acc[m][n][1]);
                pk[2] = f2bf(acc[m][n][2]); pk[3] = f2bf(acc[m][n][3]);
                *reinterpret_cast<short4v*>(
                    Vt + (((size_t)bb * HH + hh) * HDIM + hd) * SS + s0) = pk;
            }
        }
    }
}

// ---------------------------------------------------------------------------
// Flash attention, MFMA, split-KV, SWAPPED QK^T (D[row=k][col=q]) so each
// lane holds 16 k-values of its q-row: row-reduce = in-reg + 2 shfl, and the
// P relayout packs 4 consecutive k into one ds_write_b64 (8 writes/iter).
// Block = (q-tile 32 rows, head, batch), 4 waves split KV round-robin,
// private (m,l,O), LDS merge at end. K/V fragments direct from L2.
// ---------------------------------------------------------------------------
__global__ __launch_bounds__(256) void attn_mfma_kernel(
    const short* __restrict__ Q, const short* __restrict__ K,
    const short* __restrict__ Vt, short* __restrict__ ctx)
{
    const int qt = 63 - (int)blockIdx.x;  // heavy tiles first
    const int h = blockIdx.y, b = blockIdx.z;
    const int q0 = qt * 32;

    __shared__ float merge_buf[4][32][68];      // 34.8 KB (O partials, f32)
    __shared__ float mbuf[4][32], lbuf[4][32];  // 1 KB   (m, l partials)

    const int tid = threadIdx.x;
    const int w = tid >> 6, lane = tid & 63;
    const int lrow = lane & 15, lgrp = lane >> 4;
    // wave-private P relayout buffer aliases this wave's merge slice
    // (32 x 72 shorts = 4.6 KB of the 8.7 KB slice; in-order DS per wave)
    short (*Ps)[72] = reinterpret_cast<short (*)[72]>(&merge_buf[w][0][0]);

    const size_t hb = ((size_t)b * HH + h) * SS;
    const float SC = 0.125f * 1.44269504088896340736f;  // scale * log2(e)

    // Q fragments (rows q0 + mf*16 + lrow)
    short8 qf[2][2];
    const short* Qb = Q + (hb + q0) * HDIM;
    #pragma unroll
    for (int mf = 0; mf < 2; ++mf)
        #pragma unroll
        for (int kf = 0; kf < 2; ++kf)
            qf[mf][kf] = *reinterpret_cast<const short8*>(
                Qb + (mf * 16 + lrow) * HDIM + kf * 32 + lgrp * 8);

    f32x4 Oa[2][4];
    float mrun[2], lrun[2];
    #pragma unroll
    for (int mf = 0; mf < 2; ++mf) {
        #pragma unroll
        for (int nf = 0; nf < 4; ++nf) Oa[mf][nf] = (f32x4){0.f, 0.f, 0.f, 0.f};
        mrun[mf] = -INFINITY; lrun[mf] = 0.f;
    }

    const int nkb = (qt >> 1) + 1;  // kv tiles cover [0, q0+32)
    const short* Kbase = K + hb * HDIM;
    const short* Vtb = Vt + ((size_t)b * HH + h) * HDIM * SS;

    for (int kb = w; kb < nkb; kb += 4) {
        const int kv0 = kb * 64;

        // ---- K fragments direct from global ----
        short8 kfr[4][2];
        #pragma unroll
        for (int nf = 0; nf < 4; ++nf)
            #pragma unroll
            for (int kf = 0; kf < 2; ++kf)
                kfr[nf][kf] = *reinterpret_cast<const short8*>(
                    Kbase + (size_t)(kv0 + nf * 16 + lrow) * HDIM + kf * 32 + lgrp * 8);

        // ---- S^T = K Q^T : D[row=k][col=q] ----
        f32x4 s[4][2];
        #pragma unroll
        for (int nf = 0; nf < 4; ++nf)
            #pragma unroll
            for (int mf = 0; mf < 2; ++mf) s[nf][mf] = (f32x4){0.f, 0.f, 0.f, 0.f};
        #pragma unroll
        for (int nf = 0; nf < 4; ++nf)
            #pragma unroll
            for (int mf = 0; mf < 2; ++mf)
                #pragma unroll
                for (int kf = 0; kf < 2; ++kf)
                    s[nf][mf] = __builtin_amdgcn_mfma_f32_16x16x32_bf16(
                        kfr[nf][kf], qf[mf][kf], s[nf][mf], 0, 0, 0);

        // ---- scale (log2 domain) + causal mask ----
        // lane holds: q = q0 + mf*16 + lrow; k = kv0 + nf*16 + lgrp*4 + r
        const bool diag = (kv0 + 63 > q0);
        #pragma unroll
        for (int nf = 0; nf < 4; ++nf)
            #pragma unroll
            for (int mf = 0; mf < 2; ++mf)
                #pragma unroll
                for (int r = 0; r < 4; ++r) {
                    float v = s[nf][mf][r] * SC;
                    if (diag) {
                        int qg = q0 + mf * 16 + lrow;
                        int kg = kv0 + nf * 16 + lgrp * 4 + r;
                        if (kg > qg) v = -INFINITY;
                    }
                    s[nf][mf][r] = v;
                }

        // ---- online softmax: 16 k-values lane-local, reduce across lgrp ----
        float alpha[2];
        #pragma unroll
        for (int mf = 0; mf < 2; ++mf) {
            float pm = -INFINITY;
            #pragma unroll
            for (int nf = 0; nf < 4; ++nf)
                #pragma unroll
                for (int r = 0; r < 4; ++r) pm = fmaxf(pm, s[nf][mf][r]);
            pm = fmaxf(pm, __shfl_xor(pm, 16));
            pm = fmaxf(pm, __shfl_xor(pm, 32));
            float mn = fmaxf(mrun[mf], pm);
            alpha[mf] = exp2f(mrun[mf] - mn);
            mrun[mf] = mn;
            float rs = 0.f;
            #pragma unroll
            for (int nf = 0; nf < 4; ++nf)
                #pragma unroll
                for (int r = 0; r < 4; ++r) {
                    float p = exp2f(s[nf][mf][r] - mn);
                    s[nf][mf][r] = p;
                    rs += p;
                }
            rs += __shfl_xor(rs, 16);
            rs += __shfl_xor(rs, 32);
            lrun[mf] = lrun[mf] * alpha[mf] + rs;
        }

        // ---- P -> LDS (packed b64: 4 consecutive k per lane) ----
        #pragma unroll
        for (int mf = 0; mf < 2; ++mf)
            #pragma unroll
            for (int nf = 0; nf < 4; ++nf) {
                short4v pk;
                pk[0] = f2bf(s[nf][mf][0]); pk[1] = f2bf(s[nf][mf][1]);
                pk[2] = f2bf(s[nf][mf][2]); pk[3] = f2bf(s[nf][mf][3]);
                *reinterpret_cast<short4v*>(&Ps[mf * 16 + lrow][nf * 16 + lgrp * 4]) = pk;
            }
        asm volatile("s_waitcnt lgkmcnt(0)" ::: "memory");
        __builtin_amdgcn_sched_barrier(0);

        short8 pa[2][2], vb_[4][2];
        #pragma unroll
        for (int mf = 0; mf < 2; ++mf)
            #pragma unroll
            for (int kf = 0; kf < 2; ++kf)
                pa[mf][kf] = *reinterpret_cast<const short8*>(
                    &Ps[mf * 16 + lrow][kf * 32 + lgrp * 8]);

        // ---- V fragments direct from global (Vt is [hd][s]) ----
        #pragma unroll
        for (int nf = 0; nf < 4; ++nf)
            #pragma unroll
            for (int kf = 0; kf < 2; ++kf)
                vb_[nf][kf] = *reinterpret_cast<const short8*>(
                    Vtb + (size_t)(nf * 16 + lrow) * SS + kv0 + kf * 32 + lgrp * 8);

        // ---- rescale O by alpha (broadcast: softmax q=lrow -> Oa q=lgrp*4+r) ----
        #pragma unroll
        for (int mf = 0; mf < 2; ++mf)
            #pragma unroll
            for (int r = 0; r < 4; ++r) {
                float a = __shfl(alpha[mf], lgrp * 4 + r);
                #pragma unroll
                for (int nf = 0; nf < 4; ++nf) Oa[mf][nf][r] *= a;
            }

        #pragma unroll
        for (int mf = 0; mf < 2; ++mf)
            #pragma unroll
            for (int nf = 0; nf < 4; ++nf)
                #pragma unroll
                for (int kf = 0; kf < 2; ++kf)
                    Oa[mf][nf] = __builtin_amdgcn_mfma_f32_16x16x32_bf16(
                        pa[mf][kf], vb_[nf][kf], Oa[mf][nf], 0, 0, 0);
    }

    // ---- write per-wave partials (O aliases this wave's Ps region) ----
    #pragma unroll
    for (int mf = 0; mf < 2; ++mf) {
        if (lgrp == 0) {
            mbuf[w][mf * 16 + lrow] = mrun[mf];
            lbuf[w][mf * 16 + lrow] = lrun[mf];
        }
        #pragma unroll
        for (int r = 0; r < 4; ++r) {
            int row = mf * 16 + lgrp * 4 + r;
            #pragma unroll
            for (int nf = 0; nf < 4; ++nf)
                merge_buf[w][row][nf * 16 + lrow] = Oa[mf][nf][r];
        }
    }
    __syncthreads();

    // ---- merge across the 4 KV-split waves: 256 thr x 8 elems ----
    {
        const int row = tid >> 3;
        const int c0 = (tid & 7) * 8;
        float m0 = mbuf[0][row], m1 = mbuf[1][row];
        float m2 = mbuf[2][row], m3 = mbuf[3][row];
        float mg = fmaxf(fmaxf(m0, m1), fmaxf(m2, m3));
        float w0 = exp2f(m0 - mg), w1 = exp2f(m1 - mg);
        float w2 = exp2f(m2 - mg), w3 = exp2f(m3 - mg);
        float lg = w0 * lbuf[0][row] + w1 * lbuf[1][row] +
                   w2 * lbuf[2][row] + w3 * lbuf[3][row];
        float rl = 1.f / lg;
        short8 o8;
        #pragma unroll
        for (int j = 0; j < 8; ++j) {
            float o = w0 * merge_buf[0][row][c0 + j] + w1 * merge_buf[1][row][c0 + j] +
                      w2 * merge_buf[2][row][c0 + j] + w3 * merge_buf[3][row][c0 + j];
            o8[j] = f2bf(o * rl);
        }
        const int tok = b * SS + q0 + row;
        *reinterpret_cast<short8*>(ctx + (size_t)tok * DD + h * HDIM + c0) = o8;
    }
}

// ---------------------------------------------------------------------------
// Output projection with global_load_lds staging: out = ctx @ Wo + bo (f32).
// ---------------------------------------------------------------------------
__global__ __launch_bounds__(256) void out_mfma_kernel(
    const short* __restrict__ ctxbf, const short* __restrict__ Wto,
    const float* __restrict__ bo, float* __restrict__ out)
{
    const int row0 = blockIdx.y * 128;
    const int col0 = blockIdx.x * 128;
    __shared__ short As[128 * 32];
    __shared__ short Bs[128 * 32];

    const int tid = threadIdx.x;
    const int w = tid >> 6, lane = tid & 63;
    const int wm = (w >> 1) * 64, wn = (w & 1) * 64;
    const int lrow = lane & 15, lgrp = lane >> 4, lk = lgrp * 8;

    f32x4 acc[4][4];
    #pragma unroll
    for (int m = 0; m < 4; ++m)
        #pragma unroll
        for (int n = 0; n < 4; ++n) acc[m][n] = (f32x4){0.f, 0.f, 0.f, 0.f};

    for (int k0 = 0; k0 < DD; k0 += 32) {
        #pragma unroll
        for (int c = 0; c < 2; ++c) {
            int slot = c * 256 + tid;
            int r = slot >> 2, cb = (slot & 3) * 8;
            gl_lds16(ctxbf + (size_t)(row0 + r) * DD + k0 + cb, As + slot * 8);
            gl_lds16(Wto + (size_t)(col0 + r) * DD + k0 + cb, Bs + slot * 8);
        }
        __syncthreads();
        short8 af[4], bf_[4];
        #pragma unroll
        for (int m = 0; m < 4; ++m)
            af[m] = *reinterpret_cast<const short8*>(&As[(wm + m * 16 + lrow) * 32 + lk]);
        #pragma unroll
        for (int n = 0; n < 4; ++n)
            bf_[n] = *reinterpret_cast<const short8*>(&Bs[(wn + n * 16 + lrow) * 32 + lk]);
        #pragma unroll
        for (int m = 0; m < 4; ++m)
            #pragma unroll
            for (int n = 0; n < 4; ++n)
                acc[m][n] = __builtin_amdgcn_mfma_f32_16x16x32_bf16(
                    af[m], bf_[n], acc[m][n], 0, 0, 0);
        __syncthreads();
    }

    #pragma unroll
    for (int m = 0; m < 4; ++m) {
        #pragma unroll
        for (int r = 0; r < 4; ++r) {
            int tok = row0 + wm + m * 16 + lgrp * 4 + r;
            #pragma unroll
            for (int n = 0; n < 4; ++n) {
                int d = col0 + wn + n * 16 + lrow;
                out[(size_t)tok * DD + d] = acc[m][n][r] + bo[d];
            }
        }
    }
}

// ---------------------------------------------------------------------------
extern "C" void kernel_launch(void* const* d_in, const int* in_sizes, int n_in,
                              void* d_out, int out_size, void* d_ws, size_t ws_size,
                              hipStream_t stream) {
    const float* x  = (const float*)d_in[0];
    const float* Wq = (const float*)d_in[1];
    const float* Wk = (const float*)d_in[2];
    const float* Wv = (const float*)d_in[3];
    const float* Wo = (const float*)d_in[4];
    const float* bo = (const float*)d_in[5];
    float* out = (float*)d_out;

    const size_t plane = (size_t)NTOK * DD;  // 4M elems
    const size_t wsz   = (size_t)DD * DD;    // 1M elems
    short* xbf  = (short*)d_ws;
    short* Wtq  = xbf + plane;
    short* Wtk  = Wtq + wsz;
    short* Wtv  = Wtk + wsz;
    short* Wto  = Wtv + wsz;
    short* Qb   = Wto + wsz;
    short* Kb   = Qb + plane;
    short* Vtb  = Kb + plane;
    short* ctxb = Vtb + plane;
    // total = 4M + 4*1M + 4*4M shorts = 48 MB

    convert_x_kernel<<<dim3((unsigned)(plane / (256 * 8))), 256, 0, stream>>>(x, xbf);
    convw_kernel<<<dim3(16, 16, 4), 256, 0, stream>>>(Wq, Wk, Wv, Wo, Wtq, Wtk, Wtv, Wto);
    qkv_mfma_kernel<<<dim3(DD / 128, NTOK / 128, 3), 256, 0, stream>>>(
        xbf, Wtq, Wtk, Wtv, Qb, Kb, Vtb);
    attn_mfma_kernel<<<dim3(SS / 32, HH, BB), 256, 0, stream>>>(Qb, Kb, Vtb, ctxb);
    out_mfma_kernel<<<dim3(DD / 128, NTOK / 128), 256, 0, stream>>>(ctxb, Wto, bo, out);
}

// Round 14
// 224.558 us; speedup vs baseline: 13.8029x; 1.2061x over previous
//
#include <hip/hip_runtime.h>
#include <math.h>

#define BB 2
#define SS 2048
#define DD 1024
#define HH 16
#define HDIM 64
#define NTOK (BB * SS)  // 4096

typedef __attribute__((ext_vector_type(8))) short short8;
typedef __attribute__((ext_vector_type(4))) short short4v;
typedef __attribute__((ext_vector_type(4))) float f32x4;

__device__ __forceinline__ short f2bf(float f) {
    unsigned u = __builtin_bit_cast(unsigned, f);
    u = (u + 0x7FFFu + ((u >> 16) & 1u)) >> 16;  // round-to-nearest-even
    return (short)u;
}

// async global->LDS, 16B per lane. LDS dest must be wave-uniform base + lane*16.
__device__ __forceinline__ void gl_lds16(const short* g, short* l) {
    __builtin_amdgcn_global_load_lds(
        (const __attribute__((address_space(1))) void*)g,
        (__attribute__((address_space(3))) void*)l, 16, 0, 0);
}

// ---------------------------------------------------------------------------
// x (f32 [NTOK][DD]) -> bf16
// ---------------------------------------------------------------------------
__global__ __launch_bounds__(256) void convert_x_kernel(
    const float* __restrict__ x, short* __restrict__ xbf)
{
    const size_t idx = ((size_t)blockIdx.x * 256 + threadIdx.x) * 8;
    float4 a = *reinterpret_cast<const float4*>(x + idx);
    float4 b = *reinterpret_cast<const float4*>(x + idx + 4);
    short8 o;
    o[0] = f2bf(a.x); o[1] = f2bf(a.y); o[2] = f2bf(a.z); o[3] = f2bf(a.w);
    o[4] = f2bf(b.x); o[5] = f2bf(b.y); o[6] = f2bf(b.z); o[7] = f2bf(b.w);
    *reinterpret_cast<short8*>(xbf + idx) = o;
}

// ---------------------------------------------------------------------------
// W (f32 [K][N]) -> Wt (bf16 [N][K])  (transpose + convert), z selects matrix
// ---------------------------------------------------------------------------
__global__ __launch_bounds__(256) void convw_kernel(
    const float* __restrict__ Wq, const float* __restrict__ Wk,
    const float* __restrict__ Wv, const float* __restrict__ Wo,
    short* __restrict__ Wtq, short* __restrict__ Wtk,
    short* __restrict__ Wtv, short* __restrict__ Wto)
{
    const int z = blockIdx.z;
    const float* W = (z == 0) ? Wq : (z == 1) ? Wk : (z == 2) ? Wv : Wo;
    short* Wt = (z == 0) ? Wtq : (z == 1) ? Wtk : (z == 2) ? Wtv : Wto;
    const int k0 = blockIdx.x * 64, n0 = blockIdx.y * 64;
    __shared__ float T[64][65];
    const int tid = threadIdx.x;
    for (int i = tid; i < 1024; i += 256) {
        int r = i >> 4, c4 = (i & 15) * 4;
        float4 v = *reinterpret_cast<const float4*>(W + (size_t)(k0 + r) * DD + n0 + c4);
        T[r][c4 + 0] = v.x; T[r][c4 + 1] = v.y; T[r][c4 + 2] = v.z; T[r][c4 + 3] = v.w;
    }
    __syncthreads();
    for (int i = tid; i < 512; i += 256) {
        int n = i >> 3, k8 = (i & 7) * 8;
        short8 o;
        #pragma unroll
        for (int j = 0; j < 8; ++j) o[j] = f2bf(T[k8 + j][n]);
        *reinterpret_cast<short8*>(Wt + (size_t)(n0 + n) * DD + k0 + k8) = o;
    }
}

// ---------------------------------------------------------------------------
// QKV GEMM via MFMA + global_load_lds staging. 128x64 tile, BK=32, 256 thr
// (4 waves 2x2, wave tile 64x32). Q,K out: bf16 [b][h][s][hd];
// V written directly TRANSPOSED to Vt [b][h][hd][s].
// ---------------------------------------------------------------------------
__global__ __launch_bounds__(256) void qkv_mfma_kernel(
    const short* __restrict__ xbf,
    const short* __restrict__ Wtq, const short* __restrict__ Wtk,
    const short* __restrict__ Wtv,
    short* __restrict__ Q, short* __restrict__ K, short* __restrict__ Vt)
{
    const int which = blockIdx.z;
    const short* Wt = (which == 0) ? Wtq : (which == 1) ? Wtk : Wtv;

    const int row0 = blockIdx.y * 128;
    const int col0 = blockIdx.x * 64;
    __shared__ short As[128 * 32];  // linear [row][32]
    __shared__ short Bs[64 * 32];

    const int tid = threadIdx.x;
    const int w = tid >> 6, lane = tid & 63;
    const int wm = (w >> 1) * 64, wn = (w & 1) * 32;
    const int lrow = lane & 15, lgrp = lane >> 4, lk = lgrp * 8;

    f32x4 acc[4][2];
    #pragma unroll
    for (int m = 0; m < 4; ++m)
        #pragma unroll
        for (int n = 0; n < 2; ++n) acc[m][n] = (f32x4){0.f, 0.f, 0.f, 0.f};

    for (int k0 = 0; k0 < DD; k0 += 32) {
        #pragma unroll
        for (int c = 0; c < 2; ++c) {
            int slot = c * 256 + tid;
            int r = slot >> 2, cb = (slot & 3) * 8;
            gl_lds16(xbf + (size_t)(row0 + r) * DD + k0 + cb, As + slot * 8);
        }
        {
            int r = tid >> 2, cb = (tid & 3) * 8;
            gl_lds16(Wt + (size_t)(col0 + r) * DD + k0 + cb, Bs + tid * 8);
        }
        __syncthreads();  // drains vmcnt(0): LDS ready
        short8 af[4], bf_[2];
        #pragma unroll
        for (int m = 0; m < 4; ++m)
            af[m] = *reinterpret_cast<const short8*>(&As[(wm + m * 16 + lrow) * 32 + lk]);
        #pragma unroll
        for (int n = 0; n < 2; ++n)
            bf_[n] = *reinterpret_cast<const short8*>(&Bs[(wn + n * 16 + lrow) * 32 + lk]);
        #pragma unroll
        for (int m = 0; m < 4; ++m)
            #pragma unroll
            for (int n = 0; n < 2; ++n)
                acc[m][n] = __builtin_amdgcn_mfma_f32_16x16x32_bf16(
                    af[m], bf_[n], acc[m][n], 0, 0, 0);
        __syncthreads();
    }

    if (which < 2) {
        short* Out = (which == 0) ? Q : K;
        #pragma unroll
        for (int m = 0; m < 4; ++m) {
            #pragma unroll
            for (int r = 0; r < 4; ++r) {
                int tok = row0 + wm + m * 16 + lgrp * 4 + r;
                int bb = tok >> 11, s = tok & 2047;
                #pragma unroll
                for (int n = 0; n < 2; ++n) {
                    int d = col0 + wn + n * 16 + lrow;
                    int hh = d >> 6, hd = d & 63;
                    Out[(((size_t)bb * HH + hh) * SS + s) * HDIM + hd] = f2bf(acc[m][n][r]);
                }
            }
        }
    } else {
        // V: write transposed, [b][h][hd][s]; r-pack = 4 consecutive s -> short4
        #pragma unroll
        for (int m = 0; m < 4; ++m) {
            int tok0 = row0 + wm + m * 16 + lgrp * 4;
            int bb = tok0 >> 11, s0 = tok0 & 2047;
            #pragma unroll
            for (int n = 0; n < 2; ++n) {
                int d = col0 + wn + n * 16 + lrow;
                int hh = d >> 6, hd = d & 63;
                short4v pk;
                pk[0] = f2bf(acc[m][n][0]); pk[1] = f2bf(acc[m][n][1]);
                pk[2] = f2bf(acc[m][n][2]); pk[3] = f2bf(acc[m][n][3]);
                *reinterpret_cast<short4v*>(
                    Vt + (((size_t)bb * HH + hh) * HDIM + hd) * SS + s0) = pk;
            }
        }
    }
}

// ---------------------------------------------------------------------------
// Flash attention, MFMA, split-KV, swapped QK^T AND swapped PV:
//   S^T = mfma(K, Q):  D[row=k][col=q]  -> softmax per-lane (q = lane&15)
//   O^T = mfma(V^T, P): D[row=hd][col=q] -> alpha rescale is LANE-LOCAL
// (no broadcast shuffles). Block = (q-tile 32 rows, head, batch), 4 waves
// split KV round-robin, private (m,l,O), LDS merge at end.
// XCD-aware block swizzle: each XCD gets 4 contiguous (h,b) heads so its
// 4 MB L2 holds the 2 MB K/V working set (cache-capacity fit, not just
// locality). swz is bijective (2048 = 8*256).
// ---------------------------------------------------------------------------
__global__ __launch_bounds__(256) void attn_mfma_kernel(
    const short* __restrict__ Q, const short* __restrict__ K,
    const short* __restrict__ Vt, short* __restrict__ ctx)
{
    const int id = (int)(blockIdx.x + 64u * (blockIdx.y + 16u * blockIdx.z));
    const int swz = (id & 7) * 256 + (id >> 3);
    const int qt = 63 - (swz & 63);   // heavy tiles first within each XCD
    const int hb = swz >> 6;          // 0..31
    const int h = hb & 15, b = hb >> 4;
    const int q0 = qt * 32;

    __shared__ float merge_buf[4][32][68];      // 34.8 KB (O partials, f32)
    __shared__ float mbuf[4][32], lbuf[4][32];  // 1 KB   (m, l partials)

    const int tid = threadIdx.x;
    const int w = tid >> 6, lane = tid & 63;
    const int lrow = lane & 15, lgrp = lane >> 4;
    // wave-private P relayout buffer aliases this wave's merge slice
    // (32 x 72 shorts = 4.6 KB of the 8.7 KB slice; in-order DS per wave)
    short (*Ps)[72] = reinterpret_cast<short (*)[72]>(&merge_buf[w][0][0]);

    const size_t hb_off = ((size_t)b * HH + h) * SS;
    const float SC = 0.125f * 1.44269504088896340736f;  // scale * log2(e)

    // Q fragments (rows q0 + mf*16 + lrow)
    short8 qf[2][2];
    const short* Qb = Q + (hb_off + q0) * HDIM;
    #pragma unroll
    for (int mf = 0; mf < 2; ++mf)
        #pragma unroll
        for (int kf = 0; kf < 2; ++kf)
            qf[mf][kf] = *reinterpret_cast<const short8*>(
                Qb + (mf * 16 + lrow) * HDIM + kf * 32 + lgrp * 8);

    f32x4 Oa[4][2];  // [hd-frag][q-frag]  (O^T layout)
    float mrun[2], lrun[2];
    #pragma unroll
    for (int nf = 0; nf < 4; ++nf)
        #pragma unroll
        for (int mf = 0; mf < 2; ++mf) Oa[nf][mf] = (f32x4){0.f, 0.f, 0.f, 0.f};
    mrun[0] = mrun[1] = -INFINITY;
    lrun[0] = lrun[1] = 0.f;

    const int nkb = (qt >> 1) + 1;  // kv tiles cover [0, q0+32)
    const short* Kbase = K + hb_off * HDIM;
    const short* Vtb = Vt + ((size_t)b * HH + h) * HDIM * SS;

    for (int kb = w; kb < nkb; kb += 4) {
        const int kv0 = kb * 64;

        // ---- K fragments direct from global ----
        short8 kfr[4][2];
        #pragma unroll
        for (int nf = 0; nf < 4; ++nf)
            #pragma unroll
            for (int kf = 0; kf < 2; ++kf)
                kfr[nf][kf] = *reinterpret_cast<const short8*>(
                    Kbase + (size_t)(kv0 + nf * 16 + lrow) * HDIM + kf * 32 + lgrp * 8);

        // ---- S^T = K Q^T : D[row=k][col=q] ----
        f32x4 s[4][2];
        #pragma unroll
        for (int nf = 0; nf < 4; ++nf)
            #pragma unroll
            for (int mf = 0; mf < 2; ++mf) s[nf][mf] = (f32x4){0.f, 0.f, 0.f, 0.f};
        #pragma unroll
        for (int nf = 0; nf < 4; ++nf)
            #pragma unroll
            for (int mf = 0; mf < 2; ++mf)
                #pragma unroll
                for (int kf = 0; kf < 2; ++kf)
                    s[nf][mf] = __builtin_amdgcn_mfma_f32_16x16x32_bf16(
                        kfr[nf][kf], qf[mf][kf], s[nf][mf], 0, 0, 0);

        // ---- scale (log2 domain) + causal mask ----
        // lane holds: q = q0 + mf*16 + lrow; k = kv0 + nf*16 + lgrp*4 + r
        const bool diag = (kv0 + 63 > q0);
        #pragma unroll
        for (int nf = 0; nf < 4; ++nf)
            #pragma unroll
            for (int mf = 0; mf < 2; ++mf)
                #pragma unroll
                for (int r = 0; r < 4; ++r) {
                    float v = s[nf][mf][r] * SC;
                    if (diag) {
                        int qg = q0 + mf * 16 + lrow;
                        int kg = kv0 + nf * 16 + lgrp * 4 + r;
                        if (kg > qg) v = -INFINITY;
                    }
                    s[nf][mf][r] = v;
                }

        // ---- online softmax: 16 k-values lane-local, reduce across lgrp ----
        float alpha[2];
        #pragma unroll
        for (int mf = 0; mf < 2; ++mf) {
            float pm = -INFINITY;
            #pragma unroll
            for (int nf = 0; nf < 4; ++nf)
                #pragma unroll
                for (int r = 0; r < 4; ++r) pm = fmaxf(pm, s[nf][mf][r]);
            pm = fmaxf(pm, __shfl_xor(pm, 16));
            pm = fmaxf(pm, __shfl_xor(pm, 32));
            float mn = fmaxf(mrun[mf], pm);
            alpha[mf] = exp2f(mrun[mf] - mn);
            mrun[mf] = mn;
            float rs = 0.f;
            #pragma unroll
            for (int nf = 0; nf < 4; ++nf)
                #pragma unroll
                for (int r = 0; r < 4; ++r) {
                    float p = exp2f(s[nf][mf][r] - mn);
                    s[nf][mf][r] = p;
                    rs += p;
                }
            rs += __shfl_xor(rs, 16);
            rs += __shfl_xor(rs, 32);
            lrun[mf] = lrun[mf] * alpha[mf] + rs;
        }

        // ---- P -> LDS (packed b64: 4 consecutive k per lane) ----
        #pragma unroll
        for (int mf = 0; mf < 2; ++mf)
            #pragma unroll
            for (int nf = 0; nf < 4; ++nf) {
                short4v pk;
                pk[0] = f2bf(s[nf][mf][0]); pk[1] = f2bf(s[nf][mf][1]);
                pk[2] = f2bf(s[nf][mf][2]); pk[3] = f2bf(s[nf][mf][3]);
                *reinterpret_cast<short4v*>(&Ps[mf * 16 + lrow][nf * 16 + lgrp * 4]) = pk;
            }
        asm volatile("s_waitcnt lgkmcnt(0)" ::: "memory");
        __builtin_amdgcn_sched_barrier(0);

        short8 pa[2][2], vb_[4][2];
        #pragma unroll
        for (int mf = 0; mf < 2; ++mf)
            #pragma unroll
            for (int kf = 0; kf < 2; ++kf)
                pa[mf][kf] = *reinterpret_cast<const short8*>(
                    &Ps[mf * 16 + lrow][kf * 32 + lgrp * 8]);

        // ---- V fragments direct from global (Vt is [hd][s]) ----
        #pragma unroll
        for (int nf = 0; nf < 4; ++nf)
            #pragma unroll
            for (int kf = 0; kf < 2; ++kf)
                vb_[nf][kf] = *reinterpret_cast<const short8*>(
                    Vtb + (size_t)(nf * 16 + lrow) * SS + kv0 + kf * 32 + lgrp * 8);

        // ---- rescale O by alpha (lane-local: O^T cols = q = lane&15) ----
        #pragma unroll
        for (int nf = 0; nf < 4; ++nf)
            #pragma unroll
            for (int mf = 0; mf < 2; ++mf)
                #pragma unroll
                for (int r = 0; r < 4; ++r)
                    Oa[nf][mf][r] *= alpha[mf];

        // ---- O^T += V^T P : mfma(a=V^T, b=P) ----
        #pragma unroll
        for (int nf = 0; nf < 4; ++nf)
            #pragma unroll
            for (int mf = 0; mf < 2; ++mf)
                #pragma unroll
                for (int kf = 0; kf < 2; ++kf)
                    Oa[nf][mf] = __builtin_amdgcn_mfma_f32_16x16x32_bf16(
                        vb_[nf][kf], pa[mf][kf], Oa[nf][mf], 0, 0, 0);
    }

    // ---- write per-wave partials (O aliases this wave's Ps region) ----
    #pragma unroll
    for (int mf = 0; mf < 2; ++mf) {
        if (lgrp == 0) {
            mbuf[w][mf * 16 + lrow] = mrun[mf];
            lbuf[w][mf * 16 + lrow] = lrun[mf];
        }
        #pragma unroll
        for (int nf = 0; nf < 4; ++nf)
            *reinterpret_cast<f32x4*>(
                &merge_buf[w][mf * 16 + lrow][nf * 16 + lgrp * 4]) = Oa[nf][mf];
    }
    __syncthreads();

    // ---- merge across the 4 KV-split waves: 256 thr x 8 elems ----
    {
        const int row = tid >> 3;
        const int c0 = (tid & 7) * 8;
        float m0 = mbuf[0][row], m1 = mbuf[1][row];
        float m2 = mbuf[2][row], m3 = mbuf[3][row];
        float mg = fmaxf(fmaxf(m0, m1), fmaxf(m2, m3));
        float w0 = exp2f(m0 - mg), w1 = exp2f(m1 - mg);
        float w2 = exp2f(m2 - mg), w3 = exp2f(m3 - mg);
        float lg = w0 * lbuf[0][row] + w1 * lbuf[1][row] +
                   w2 * lbuf[2][row] + w3 * lbuf[3][row];
        float rl = 1.f / lg;
        short8 o8;
        #pragma unroll
        for (int j = 0; j < 8; ++j) {
            float o = w0 * merge_buf[0][row][c0 + j] + w1 * merge_buf[1][row][c0 + j] +
                      w2 * merge_buf[2][row][c0 + j] + w3 * merge_buf[3][row][c0 + j];
            o8[j] = f2bf(o * rl);
        }
        const int tok = b * SS + q0 + row;
        *reinterpret_cast<short8*>(ctx + (size_t)tok * DD + h * HDIM + c0) = o8;
    }
}

// ---------------------------------------------------------------------------
// Output projection, 64x64 tile (1024 blocks, 4/CU): out = ctx @ Wo + bo.
// ---------------------------------------------------------------------------
__global__ __launch_bounds__(256) void out_mfma_kernel(
    const short* __restrict__ ctxbf, const short* __restrict__ Wto,
    const float* __restrict__ bo, float* __restrict__ out)
{
    const int row0 = blockIdx.y * 64;
    const int col0 = blockIdx.x * 64;
    __shared__ short As[64 * 32];
    __shared__ short Bs[64 * 32];

    const int tid = threadIdx.x;
    const int w = tid >> 6, lane = tid & 63;
    const int wm = (w >> 1) * 32, wn = (w & 1) * 32;
    const int lrow = lane & 15, lgrp = lane >> 4, lk = lgrp * 8;

    f32x4 acc[2][2];
    #pragma unroll
    for (int m = 0; m < 2; ++m)
        #pragma unroll
        for (int n = 0; n < 2; ++n) acc[m][n] = (f32x4){0.f, 0.f, 0.f, 0.f};

    for (int k0 = 0; k0 < DD; k0 += 32) {
        {
            int r = tid >> 2, cb = (tid & 3) * 8;
            gl_lds16(ctxbf + (size_t)(row0 + r) * DD + k0 + cb, As + tid * 8);
            gl_lds16(Wto + (size_t)(col0 + r) * DD + k0 + cb, Bs + tid * 8);
        }
        __syncthreads();
        short8 af[2], bf_[2];
        #pragma unroll
        for (int m = 0; m < 2; ++m)
            af[m] = *reinterpret_cast<const short8*>(&As[(wm + m * 16 + lrow) * 32 + lk]);
        #pragma unroll
        for (int n = 0; n < 2; ++n)
            bf_[n] = *reinterpret_cast<const short8*>(&Bs[(wn + n * 16 + lrow) * 32 + lk]);
        #pragma unroll
        for (int m = 0; m < 2; ++m)
            #pragma unroll
            for (int n = 0; n < 2; ++n)
                acc[m][n] = __builtin_amdgcn_mfma_f32_16x16x32_bf16(
                    af[m], bf_[n], acc[m][n], 0, 0, 0);
        __syncthreads();
    }

    #pragma unroll
    for (int m = 0; m < 2; ++m) {
        #pragma unroll
        for (int r = 0; r < 4; ++r) {
            int tok = row0 + wm + m * 16 + lgrp * 4 + r;
            #pragma unroll
            for (int n = 0; n < 2; ++n) {
                int d = col0 + wn + n * 16 + lrow;
                out[(size_t)tok * DD + d] = acc[m][n][r] + bo[d];
            }
        }
    }
}

// ---------------------------------------------------------------------------
extern "C" void kernel_launch(void* const* d_in, const int* in_sizes, int n_in,
                              void* d_out, int out_size, void* d_ws, size_t ws_size,
                              hipStream_t stream) {
    const float* x  = (const float*)d_in[0];
    const float* Wq = (const float*)d_in[1];
    const float* Wk = (const float*)d_in[2];
    const float* Wv = (const float*)d_in[3];
    const float* Wo = (const float*)d_in[4];
    const float* bo = (const float*)d_in[5];
    float* out = (float*)d_out;

    const size_t plane = (size_t)NTOK * DD;  // 4M elems
    const size_t wsz   = (size_t)DD * DD;    // 1M elems
    short* xbf  = (short*)d_ws;
    short* Wtq  = xbf + plane;
    short* Wtk  = Wtq + wsz;
    short* Wtv  = Wtk + wsz;
    short* Wto  = Wtv + wsz;
    short* Qb   = Wto + wsz;
    short* Kb   = Qb + plane;
    short* Vtb  = Kb + plane;
    short* ctxb = Vtb + plane;
    // total = 4M + 4*1M + 4*4M shorts = 48 MB

    convert_x_kernel<<<dim3((unsigned)(plane / (256 * 8))), 256, 0, stream>>>(x, xbf);
    convw_kernel<<<dim3(16, 16, 4), 256, 0, stream>>>(Wq, Wk, Wv, Wo, Wtq, Wtk, Wtv, Wto);
    qkv_mfma_kernel<<<dim3(DD / 64, NTOK / 128, 3), 256, 0, stream>>>(
        xbf, Wtq, Wtk, Wtv, Qb, Kb, Vtb);
    attn_mfma_kernel<<<dim3(SS / 32, HH, BB), 256, 0, stream>>>(Qb, Kb, Vtb, ctxb);
    out_mfma_kernel<<<dim3(DD / 64, NTOK / 64), 256, 0, stream>>>(ctxb, Wto, bo, out);
}